// Round 20
// baseline (461.042 us; speedup 1.0000x reference)
//
#include <hip/hip_runtime.h>

#define NNODES 12288
#define ETOT   73728
#define NGR    1024
#define LOG2E  1.442695041f
#define LN2    0.6931471806f

typedef __attribute__((ext_vector_type(8))) short short8;
typedef __attribute__((ext_vector_type(4))) float f32x4;

__device__ __forceinline__ unsigned short f2b(float f) {
  return __builtin_bit_cast(unsigned short, (__bf16)f);
}
__device__ __forceinline__ float b2f(unsigned short u) {
  return __uint_as_float(((unsigned)u) << 16);
}
__device__ __forceinline__ void load_lds16(const void* g, void* l) {
  __builtin_amdgcn_global_load_lds(
      (const __attribute__((address_space(1))) unsigned int*)g,
      (__attribute__((address_space(3))) unsigned int*)l, 16, 0, 0);
}
// LDS-only barrier: waits LDS ops, leaves global stores/loads in flight.
__device__ __forceinline__ void lds_barrier() {
  asm volatile("s_waitcnt lgkmcnt(0)" ::: "memory");
  __builtin_amdgcn_s_barrier();
}

// proj layout: [colblk = col>>7][node][col&127]
__device__ __forceinline__ const unsigned short* pnode(
    const unsigned short* P, int col0, int node) {
  return P + ((size_t)(col0 >> 7) * NNODES + node) * 128 + (col0 & 127);
}

// ---------------------------------------------------------------------------
// Pack (unchanged): weights in MFMA-fragment order
// ---------------------------------------------------------------------------
__global__ void pack_kernel(
    const float* __restrict__ gat_Wl, const float* __restrict__ gat_Wr,
    const float* __restrict__ cg_Wf, const float* __restrict__ cg_Ws,
    const float* __restrict__ node_W, const float* __restrict__ enc_W,
    const float* __restrict__ fin_W1,
    const float* __restrict__ gat_bl, const float* __restrict__ gat_br,
    const float* __restrict__ cg_bf, const float* __restrict__ cg_bs,
    const float* __restrict__ x_my, const float* __restrict__ x_opp,
    unsigned short* __restrict__ wt_my, unsigned short* __restrict__ wt_opp,
    unsigned short* __restrict__ node_wt, unsigned short* __restrict__ enc_wt,
    unsigned short* __restrict__ fin_w1t,
    float* __restrict__ bias_my, float* __restrict__ bias_opp,
    unsigned short* __restrict__ xb)
{
  int idx = blockIdx.x * 256 + threadIdx.x;
  if (idx < 2 * 2359296) {
    int which = idx >= 2359296;
    int t = which ? idx - 2359296 : idx;
    int l = t / 786432;
    int r = t - l * 786432;
    int j = r & 7, lane = (r >> 3) & 63, blk = r >> 9;
    int kb = blk & 7, nb = blk >> 3;
    int n = nb * 16 + (lane & 15);
    int k = kb * 32 + (lane >> 4) * 8 + j;
    float v;
    if (!which) {
      if (n < 1024)      v = gat_Wl[((l*2+0)*256 + k)*1024 + n];
      else if (n < 2048) v = gat_Wr[((l*2+1)*256 + k)*1024 + (n-1024)];
      else if (n < 2304) v = cg_Wf[((l*2+0)*512 + 256 + k)*256 + (n-2048)];
      else if (n < 2560) v = cg_Ws[((l*2+0)*512 + 256 + k)*256 + (n-2304)];
      else if (n < 2816) v = cg_Wf[((l*2+1)*512 + k)*256 + (n-2560)];
      else               v = cg_Ws[((l*2+1)*512 + k)*256 + (n-2816)];
      wt_my[t] = f2b(v);
    } else {
      if (n < 1024)      v = gat_Wr[((l*2+0)*256 + k)*1024 + n];
      else if (n < 2048) v = gat_Wl[((l*2+1)*256 + k)*1024 + (n-1024)];
      else if (n < 2304) v = cg_Wf[((l*2+0)*512 + k)*256 + (n-2048)];
      else if (n < 2560) v = cg_Ws[((l*2+0)*512 + k)*256 + (n-2304)];
      else if (n < 2816) v = cg_Wf[((l*2+1)*512 + 256 + k)*256 + (n-2560)];
      else               v = cg_Ws[((l*2+1)*512 + 256 + k)*256 + (n-2816)];
      wt_opp[t] = f2b(v);
    }
    return;
  }
  idx -= 2 * 2359296;
  if (idx < 196608) {
    int l = idx / 65536, r = idx - l * 65536;
    int j = r & 7, lane = (r >> 3) & 63, blk = r >> 9;
    int kb = blk & 7, nb = blk >> 3;
    int n = nb * 16 + (lane & 15);
    int k = kb * 32 + (lane >> 4) * 8 + j;
    node_wt[idx] = f2b(node_W[(l*256 + k)*256 + n]);
    return;
  }
  idx -= 196608;
  if (idx < 8192) {
    int r = idx;
    int j = r & 7, lane = (r >> 3) & 63, blk = r >> 9;
    int nb = blk;
    int n = nb * 16 + (lane & 15);
    int k = (lane >> 4) * 8 + j;
    enc_wt[idx] = f2b(enc_W[k*256 + n]);
    return;
  }
  idx -= 8192;
  if (idx < 32768) {
    int r = idx;
    int j = r & 7, lane = (r >> 3) & 63, blk = r >> 9;
    int kb = blk & 7, nb = blk >> 3;
    int n = nb * 16 + (lane & 15);
    int k = kb * 32 + (lane >> 4) * 8 + j;
    fin_w1t[idx] = f2b(fin_W1[k*128 + n]);
    return;
  }
  idx -= 32768;
  if (idx < 9216) {
    int l = idx / 3072, n = idx - l * 3072;
    float v;
    if (n < 1024)      v = gat_bl[(l*2+0)*1024 + n];
    else if (n < 2048) v = gat_br[(l*2+1)*1024 + (n-1024)];
    else if (n < 2560) v = 0.f;
    else if (n < 2816) v = cg_bf[(l*2+1)*256 + (n-2560)];
    else               v = cg_bs[(l*2+1)*256 + (n-2816)];
    bias_my[idx] = v;
    return;
  }
  idx -= 9216;
  if (idx < 9216) {
    int l = idx / 3072, n = idx - l * 3072;
    float v;
    if (n < 1024)      v = gat_br[(l*2+0)*1024 + n];
    else if (n < 2048) v = gat_bl[(l*2+1)*1024 + (n-1024)];
    else if (n < 2304) v = cg_bf[(l*2+0)*256 + (n-2048)];
    else if (n < 2560) v = cg_bs[(l*2+0)*256 + (n-2304)];
    else               v = 0.f;
    bias_opp[idx] = v;
    return;
  }
  idx -= 9216;
  if (idx < 2 * 393216) {
    xb[idx] = f2b(idx < 393216 ? x_my[idx] : x_opp[idx - 393216]);
  }
}

// ---------------------------------------------------------------------------
// bf16 GEMM v7 (unchanged): used for enc/fin (small-N, row-major out).
// ---------------------------------------------------------------------------
__global__ __launch_bounds__(256) void gemm64(
    const unsigned short* __restrict__ A, const unsigned short* __restrict__ Ab,
    int lda,
    const unsigned short* __restrict__ Wp, const unsigned short* __restrict__ Wpb,
    const float* __restrict__ bias, const float* __restrict__ biasb,
    unsigned short* __restrict__ C, unsigned short* __restrict__ Cb,
    int ldc, int K, int act, int bx_split)
{
  __shared__ __align__(16) unsigned short lA[64 * 256];
  const int tid = threadIdx.x;
  const int lane = tid & 63;
  const int w = tid >> 6;
  const int wr = w >> 1, wc = w & 1;
  const int r0 = lane & 15, kq = lane >> 4;
  const int KT = K >> 5;
  const int gm = (K >> 3) - 1;
  const int rmask = gm > 7 ? 7 : gm;
  const int gsh = __popc((unsigned)gm);

  const unsigned short *Ap, *Wsel;
  const float* bp;
  unsigned short* Cp;
  int tileM;
  if ((int)blockIdx.x < bx_split) {
    Ap = A;  Wsel = Wp;  bp = bias;  Cp = C;  tileM = blockIdx.x * 64;
  } else {
    Ap = Ab; Wsel = Wpb; bp = biasb; Cp = Cb; tileM = (blockIdx.x - bx_split) * 64;
  }
  const int tileN = blockIdx.y * 128;

  for (int rd = 0; rd < KT; ++rd) {
    int idx = rd * 256 + tid;
    int row = idx >> gsh;
    int g = idx & gm;
    load_lds16(Ap + (size_t)(tileM + row) * lda + ((g ^ (row & rmask)) << 3),
               (char*)lA + idx * 16);
  }

  const int nblk0 = (tileN >> 4) + wc * 4;
  const unsigned short* wn0 = Wsel + ((size_t)(nblk0 + 0) * KT * 64 + lane) * 8;
  const unsigned short* wn1 = Wsel + ((size_t)(nblk0 + 1) * KT * 64 + lane) * 8;
  const unsigned short* wn2 = Wsel + ((size_t)(nblk0 + 2) * KT * 64 + lane) * 8;
  const unsigned short* wn3 = Wsel + ((size_t)(nblk0 + 3) * KT * 64 + lane) * 8;

  short8 b0_0 = *(const short8*)wn0;
  short8 b0_1 = *(const short8*)wn1;
  short8 b0_2 = *(const short8*)wn2;
  short8 b0_3 = *(const short8*)wn3;
  short8 b1_0 = b0_0, b1_1 = b0_1, b1_2 = b0_2, b1_3 = b0_3;
  if (KT > 1) {
    b1_0 = *(const short8*)(wn0 + 512);
    b1_1 = *(const short8*)(wn1 + 512);
    b1_2 = *(const short8*)(wn2 + 512);
    b1_3 = *(const short8*)(wn3 + 512);
  }

  f32x4 acc[2][4];
#pragma unroll
  for (int m = 0; m < 2; ++m)
#pragma unroll
    for (int n = 0; n < 4; ++n)
      acc[m][n] = (f32x4){0.f, 0.f, 0.f, 0.f};

  const int rb0 = (wr * 32 + r0) * K;
  const int rb1 = (wr * 32 + 16 + r0) * K;
  const int rx = r0 & rmask;

  __syncthreads();

  for (int kt = 0; kt < KT; ++kt) {
    short8 b2_0 = b1_0, b2_1 = b1_1, b2_2 = b1_2, b2_3 = b1_3;
    if (kt + 2 < KT) {
      const int o = (kt + 2) * 512;
      b2_0 = *(const short8*)(wn0 + o);
      b2_1 = *(const short8*)(wn1 + o);
      b2_2 = *(const short8*)(wn2 + o);
      b2_3 = *(const short8*)(wn3 + o);
    }
    const int p = (((kt << 2) + kq) ^ rx) * 8;
    short8 af0 = *(const short8*)&lA[rb0 + p];
    short8 af1 = *(const short8*)&lA[rb1 + p];
    acc[0][0] = __builtin_amdgcn_mfma_f32_16x16x32_bf16(b0_0, af0, acc[0][0], 0, 0, 0);
    acc[0][1] = __builtin_amdgcn_mfma_f32_16x16x32_bf16(b0_1, af0, acc[0][1], 0, 0, 0);
    acc[0][2] = __builtin_amdgcn_mfma_f32_16x16x32_bf16(b0_2, af0, acc[0][2], 0, 0, 0);
    acc[0][3] = __builtin_amdgcn_mfma_f32_16x16x32_bf16(b0_3, af0, acc[0][3], 0, 0, 0);
    acc[1][0] = __builtin_amdgcn_mfma_f32_16x16x32_bf16(b0_0, af1, acc[1][0], 0, 0, 0);
    acc[1][1] = __builtin_amdgcn_mfma_f32_16x16x32_bf16(b0_1, af1, acc[1][1], 0, 0, 0);
    acc[1][2] = __builtin_amdgcn_mfma_f32_16x16x32_bf16(b0_2, af1, acc[1][2], 0, 0, 0);
    acc[1][3] = __builtin_amdgcn_mfma_f32_16x16x32_bf16(b0_3, af1, acc[1][3], 0, 0, 0);
    b0_0 = b1_0; b0_1 = b1_1; b0_2 = b1_2; b0_3 = b1_3;
    b1_0 = b2_0; b1_1 = b2_1; b1_2 = b2_2; b1_3 = b2_3;
  }

  unsigned short* cT = lA;
  __syncthreads();
#pragma unroll
  for (int m = 0; m < 2; ++m) {
    const int rl = wr * 32 + m * 16 + r0;
#pragma unroll
    for (int n = 0; n < 4; ++n) {
      const int cl = wc * 64 + n * 16 + kq * 4;
      const f32x4 bv = *(const f32x4*)&bp[tileN + cl];
      float v0 = acc[m][n][0] + bv[0];
      float v1 = acc[m][n][1] + bv[1];
      float v2 = acc[m][n][2] + bv[2];
      float v3 = acc[m][n][3] + bv[3];
      if (act) {
        v0 = v0 > 0.f ? v0 : 128.f * v0;
        v1 = v1 > 0.f ? v1 : 128.f * v1;
        v2 = v2 > 0.f ? v2 : 128.f * v2;
        v3 = v3 > 0.f ? v3 : 128.f * v3;
      }
      uint2 pk;
      pk.x = (unsigned)f2b(v0) | ((unsigned)f2b(v1) << 16);
      pk.y = (unsigned)f2b(v2) | ((unsigned)f2b(v3) << 16);
      *(uint2*)&cT[rl * 132 + cl] = pk;
    }
  }
  __syncthreads();
#pragma unroll
  for (int it = 0; it < 4; ++it) {
    const int idx = it * 256 + tid;
    const int row = idx >> 4, ch = idx & 15;
    const uint4 val = *(const uint4*)&cT[row * 132 + ch * 8];
    *(uint4*)(Cp + (size_t)(tileM + row) * ldc + tileN + ch * 8) = val;
  }
}

// ---------------------------------------------------------------------------
// gemm64p v2: persistent-A proj GEMM with LDS-ONLY barriers in the nn loop —
// global stores stay in flight across iterations (no vmcnt(0) drain).
// ---------------------------------------------------------------------------
__global__ __launch_bounds__(256) void gemm64p(
    const unsigned short* __restrict__ A, const unsigned short* __restrict__ Ab,
    const unsigned short* __restrict__ Wp, const unsigned short* __restrict__ Wpb,
    const float* __restrict__ bias, const float* __restrict__ biasb,
    unsigned short* __restrict__ C, unsigned short* __restrict__ Cb,
    int bx_split)
{
  const int K = 256, KT = 8;
  __shared__ __align__(16) unsigned short lA[64 * 256];
  __shared__ __align__(16) unsigned short cT[64 * 132];
  const int tid = threadIdx.x;
  const int lane = tid & 63;
  const int w = tid >> 6;
  const int wr = w >> 1, wc = w & 1;
  const int r0 = lane & 15, kq = lane >> 4;

  const unsigned short *Ap, *Wsel;
  const float* bp;
  unsigned short* Cp;
  int tileM;
  if ((int)blockIdx.x < bx_split) {
    Ap = A;  Wsel = Wp;  bp = bias;  Cp = C;  tileM = blockIdx.x * 64;
  } else {
    Ap = Ab; Wsel = Wpb; bp = biasb; Cp = Cb; tileM = (blockIdx.x - bx_split) * 64;
  }

  for (int rd = 0; rd < KT; ++rd) {
    int idx = rd * 256 + tid;
    int row = idx >> 5;
    int g = idx & 31;
    load_lds16(Ap + (size_t)(tileM + row) * K + ((g ^ (row & 7)) << 3),
               (char*)lA + idx * 16);
  }

  const int rb0 = (wr * 32 + r0) * K;
  const int rb1 = (wr * 32 + 16 + r0) * K;
  const int rx = r0 & 7;

  __syncthreads();   // A tile resident (global_load_lds needs full drain)

  for (int nn = 0; nn < 12; ++nn) {
    const int cb = (int)blockIdx.y * 12 + nn;
    const int tileN = cb * 128;
    const int nblk0 = (tileN >> 4) + wc * 4;
    const unsigned short* wn0 = Wsel + ((size_t)(nblk0 + 0) * KT * 64 + lane) * 8;
    const unsigned short* wn1 = Wsel + ((size_t)(nblk0 + 1) * KT * 64 + lane) * 8;
    const unsigned short* wn2 = Wsel + ((size_t)(nblk0 + 2) * KT * 64 + lane) * 8;
    const unsigned short* wn3 = Wsel + ((size_t)(nblk0 + 3) * KT * 64 + lane) * 8;

    short8 b0_0 = *(const short8*)wn0;
    short8 b0_1 = *(const short8*)wn1;
    short8 b0_2 = *(const short8*)wn2;
    short8 b0_3 = *(const short8*)wn3;
    short8 b1_0 = *(const short8*)(wn0 + 512);
    short8 b1_1 = *(const short8*)(wn1 + 512);
    short8 b1_2 = *(const short8*)(wn2 + 512);
    short8 b1_3 = *(const short8*)(wn3 + 512);

    f32x4 acc[2][4];
#pragma unroll
    for (int m = 0; m < 2; ++m)
#pragma unroll
      for (int n = 0; n < 4; ++n)
        acc[m][n] = (f32x4){0.f, 0.f, 0.f, 0.f};

    for (int kt = 0; kt < KT; ++kt) {
      short8 b2_0 = b1_0, b2_1 = b1_1, b2_2 = b1_2, b2_3 = b1_3;
      if (kt + 2 < KT) {
        const int o = (kt + 2) * 512;
        b2_0 = *(const short8*)(wn0 + o);
        b2_1 = *(const short8*)(wn1 + o);
        b2_2 = *(const short8*)(wn2 + o);
        b2_3 = *(const short8*)(wn3 + o);
      }
      const int p = (((kt << 2) + kq) ^ rx) * 8;
      short8 af0 = *(const short8*)&lA[rb0 + p];
      short8 af1 = *(const short8*)&lA[rb1 + p];
      acc[0][0] = __builtin_amdgcn_mfma_f32_16x16x32_bf16(b0_0, af0, acc[0][0], 0, 0, 0);
      acc[0][1] = __builtin_amdgcn_mfma_f32_16x16x32_bf16(b0_1, af0, acc[0][1], 0, 0, 0);
      acc[0][2] = __builtin_amdgcn_mfma_f32_16x16x32_bf16(b0_2, af0, acc[0][2], 0, 0, 0);
      acc[0][3] = __builtin_amdgcn_mfma_f32_16x16x32_bf16(b0_3, af0, acc[0][3], 0, 0, 0);
      acc[1][0] = __builtin_amdgcn_mfma_f32_16x16x32_bf16(b0_0, af1, acc[1][0], 0, 0, 0);
      acc[1][1] = __builtin_amdgcn_mfma_f32_16x16x32_bf16(b0_1, af1, acc[1][1], 0, 0, 0);
      acc[1][2] = __builtin_amdgcn_mfma_f32_16x16x32_bf16(b0_2, af1, acc[1][2], 0, 0, 0);
      acc[1][3] = __builtin_amdgcn_mfma_f32_16x16x32_bf16(b0_3, af1, acc[1][3], 0, 0, 0);
      b0_0 = b1_0; b0_1 = b1_1; b0_2 = b1_2; b0_3 = b1_3;
      b1_0 = b2_0; b1_1 = b2_1; b1_2 = b2_2; b1_3 = b2_3;
    }

    lds_barrier();   // prior nn's cT reads complete (LDS-only; stores fly on)
#pragma unroll
    for (int m = 0; m < 2; ++m) {
      const int rl = wr * 32 + m * 16 + r0;
#pragma unroll
      for (int n = 0; n < 4; ++n) {
        const int cl = wc * 64 + n * 16 + kq * 4;
        const f32x4 bv = *(const f32x4*)&bp[tileN + cl];
        uint2 pk;
        pk.x = (unsigned)f2b(acc[m][n][0] + bv[0]) |
               ((unsigned)f2b(acc[m][n][1] + bv[1]) << 16);
        pk.y = (unsigned)f2b(acc[m][n][2] + bv[2]) |
               ((unsigned)f2b(acc[m][n][3] + bv[3]) << 16);
        *(uint2*)&cT[rl * 132 + cl] = pk;
      }
    }
    lds_barrier();   // cT writes visible (LDS-only)
    unsigned short* dstb = Cp + ((size_t)cb * NNODES + tileM) * 128;
#pragma unroll
    for (int it = 0; it < 4; ++it) {
      const int idx = it * 256 + tid;
      const uint4 val = *(const uint4*)&cT[(idx >> 4) * 132 + (idx & 15) * 8];
      *(uint4*)(dstb + (size_t)idx * 8) = val;
    }
  }
}

// ---------------------------------------------------------------------------
// GATv2 edge stage v10 (unchanged): group-per-(d,h), shuffle softmax.
// ---------------------------------------------------------------------------
#define SX 260
__global__ __launch_bounds__(256) void gat_edge(
    const unsigned short* __restrict__ proj_my,
    const unsigned short* __restrict__ proj_op,
    const int* __restrict__ e_beats, const int* __restrict__ e_rl,
    const float* __restrict__ attL, const float* __restrict__ gbiasL,
    unsigned short* __restrict__ gat_op, unsigned short* __restrict__ gat_my)
{
  __shared__ __align__(16) unsigned short xl[48 * SX];
  __shared__ __align__(16) float attS[4 * SX];
  __shared__ __align__(16) float A2f[12 * 48];
  __shared__ int multI[144];
  __shared__ unsigned char srcG[12][12];
  __shared__ unsigned char multG[12][12];
  __shared__ int cntG[12];
  const int bid = blockIdx.x, tid = threadIdx.x;
  const int dir = bid >= NGR;
  const int g = dir ? bid - NGR : bid;
  const int base = g * 12;

  const unsigned short *Psrc, *Pdst;
  int pcol0;
  const int* edges;
  const float* att;
  const float* gbias;
  unsigned short* outp;
  if (!dir) {
    Psrc = proj_my; Pdst = proj_op; pcol0 = 0;
    edges = e_beats; att = attL; gbias = gbiasL; outp = gat_op;
  } else {
    Psrc = proj_op; Pdst = proj_my; pcol0 = 1024;
    edges = e_rl; att = attL + 1024; gbias = gbiasL + 256; outp = gat_my;
  }

  if (tid < 144) multI[tid] = 0;
  for (int i = tid; i < 576; i += 256) A2f[i] = 0.f;
  __syncthreads();
  if (tid < 72) {
    const int s = edges[g * 72 + tid] - base;
    const int d = edges[ETOT + g * 72 + tid] - base;
    atomicAdd(&multI[d * 12 + s], 1);
  }
  for (int i = tid; i < 1024; i += 256)
    attS[(i >> 8) * SX + (i & 255)] = att[i];
  for (int i = tid; i < 3072; i += 256) {
    int s = i >> 8, c4 = (i & 255) * 4;
    int h = c4 >> 8, cc = c4 & 255;
    *(ushort4*)&xl[(h * 12 + s) * SX + cc] =
        *(const ushort4*)pnode(Psrc, pcol0 + c4, base + s);
  }
  __syncthreads();

  if (tid < 12) {
    int n = 0;
    for (int s = 0; s < 12; ++s) {
      const int m = multI[tid * 12 + s];
      if (m > 0) { srcG[tid][n] = (unsigned char)s; multG[tid][n] = (unsigned char)m; ++n; }
    }
    cntG[tid] = n;
  }
  __syncthreads();

  for (int r = 0; r < 3; ++r) {
    const int slot = r * 256 + tid;
    const int g16 = slot >> 4, lane16 = slot & 15;
    const int d = g16 >> 2, h = g16 & 3;
    const int cnt = cntG[d];
    const int ch0 = lane16 * 16;
    const unsigned short* prp = pnode(Pdst, pcol0 + h * 256 + ch0, base + d);
    const ushort4 xr0 = *(const ushort4*)(prp);
    const ushort4 xr1 = *(const ushort4*)(prp + 4);
    const ushort4 xr2 = *(const ushort4*)(prp + 8);
    const ushort4 xr3 = *(const ushort4*)(prp + 12);
    const float* pa = &attS[h * SX + ch0];
    const f32x4 at0 = *(const f32x4*)(pa);
    const f32x4 at1 = *(const f32x4*)(pa + 4);
    const f32x4 at2 = *(const f32x4*)(pa + 8);
    const f32x4 at3 = *(const f32x4*)(pa + 12);

    float myalpha = -1e30f;
    for (int j = 0; j < cnt; ++j) {
      const int s = srcG[d][j];
      const unsigned short* pl = &xl[(h * 12 + s) * SX + ch0];
      float p = 0.f;
      {
        ushort4 a4 = *(const ushort4*)(pl);
        float v0 = b2f(a4.x) + b2f(xr0.x); v0 = fmaxf(v0, 0.2f * v0);
        float v1 = b2f(a4.y) + b2f(xr0.y); v1 = fmaxf(v1, 0.2f * v1);
        float v2 = b2f(a4.z) + b2f(xr0.z); v2 = fmaxf(v2, 0.2f * v2);
        float v3 = b2f(a4.w) + b2f(xr0.w); v3 = fmaxf(v3, 0.2f * v3);
        p = fmaf(v0, at0[0], p); p = fmaf(v1, at0[1], p);
        p = fmaf(v2, at0[2], p); p = fmaf(v3, at0[3], p);
      }
      {
        ushort4 a4 = *(const ushort4*)(pl + 4);
        float v0 = b2f(a4.x) + b2f(xr1.x); v0 = fmaxf(v0, 0.2f * v0);
        float v1 = b2f(a4.y) + b2f(xr1.y); v1 = fmaxf(v1, 0.2f * v1);
        float v2 = b2f(a4.z) + b2f(xr1.z); v2 = fmaxf(v2, 0.2f * v2);
        float v3 = b2f(a4.w) + b2f(xr1.w); v3 = fmaxf(v3, 0.2f * v3);
        p = fmaf(v0, at1[0], p); p = fmaf(v1, at1[1], p);
        p = fmaf(v2, at1[2], p); p = fmaf(v3, at1[3], p);
      }
      {
        ushort4 a4 = *(const ushort4*)(pl + 8);
        float v0 = b2f(a4.x) + b2f(xr2.x); v0 = fmaxf(v0, 0.2f * v0);
        float v1 = b2f(a4.y) + b2f(xr2.y); v1 = fmaxf(v1, 0.2f * v1);
        float v2 = b2f(a4.z) + b2f(xr2.z); v2 = fmaxf(v2, 0.2f * v2);
        float v3 = b2f(a4.w) + b2f(xr2.w); v3 = fmaxf(v3, 0.2f * v3);
        p = fmaf(v0, at2[0], p); p = fmaf(v1, at2[1], p);
        p = fmaf(v2, at2[2], p); p = fmaf(v3, at2[3], p);
      }
      {
        ushort4 a4 = *(const ushort4*)(pl + 12);
        float v0 = b2f(a4.x) + b2f(xr3.x); v0 = fmaxf(v0, 0.2f * v0);
        float v1 = b2f(a4.y) + b2f(xr3.y); v1 = fmaxf(v1, 0.2f * v1);
        float v2 = b2f(a4.z) + b2f(xr3.z); v2 = fmaxf(v2, 0.2f * v2);
        float v3 = b2f(a4.w) + b2f(xr3.w); v3 = fmaxf(v3, 0.2f * v3);
        p = fmaf(v0, at3[0], p); p = fmaf(v1, at3[1], p);
        p = fmaf(v2, at3[2], p); p = fmaf(v3, at3[3], p);
      }
#pragma unroll
      for (int off = 1; off < 16; off <<= 1) p += __shfl_xor(p, off, 64);
      if (j == lane16) myalpha = p * LOG2E;
    }
    float m = myalpha;
#pragma unroll
    for (int off = 1; off < 16; off <<= 1) m = fmaxf(m, __shfl_xor(m, off, 64));
    const float wv = __builtin_amdgcn_exp2f(myalpha - m);
    const float mw = (lane16 < cnt) ? (float)multG[d][lane16] * wv : 0.f;
    float den = mw;
#pragma unroll
    for (int off = 1; off < 16; off <<= 1) den += __shfl_xor(den, off, 64);
    const float inv = 0.25f * __builtin_amdgcn_rcpf(den + 1e-16f);
    if (lane16 < cnt) A2f[d * 48 + h * 12 + srcG[d][lane16]] = mw * inv;
  }
  __syncthreads();

  {
    const int c = tid;
    float xlv[48];
#pragma unroll
    for (int j = 0; j < 48; ++j) xlv[j] = b2f(xl[j * SX + c]);
    const float gb = gbias[c];
#pragma unroll
    for (int d = 0; d < 12; ++d) {
      const f32x4* arow = (const f32x4*)&A2f[d * 48];
      float s = 0.f;
#pragma unroll
      for (int jj = 0; jj < 12; ++jj) {
        f32x4 a4 = arow[jj];
        s = fmaf(a4.x, xlv[jj * 4 + 0], s);
        s = fmaf(a4.y, xlv[jj * 4 + 1], s);
        s = fmaf(a4.z, xlv[jj * 4 + 2], s);
        s = fmaf(a4.w, xlv[jj * 4 + 3], s);
      }
      outp[(size_t)(base + d) * 256 + c] = f2b(s + gb);
    }
  }
}

// ---------------------------------------------------------------------------
// cg_fused v2 (unchanged from R19): dedup'd CGConv combine + node MFMA.
// ---------------------------------------------------------------------------
__global__ __launch_bounds__(256) void cg_fused(
    const unsigned short* __restrict__ proj_my,
    const unsigned short* __restrict__ proj_op,
    unsigned short* __restrict__ Hmy, unsigned short* __restrict__ Hopp,
    const unsigned short* __restrict__ gat_my, const unsigned short* __restrict__ gat_op,
    const int* __restrict__ e_loses, const int* __restrict__ e_rb,
    const unsigned short* __restrict__ node_wtL, const float* __restrict__ node_bL)
{
  __shared__ __align__(8) unsigned short df[3072], dsb[3072];
  __shared__ __align__(8) unsigned short sfb[3072], ssb[3072];
  __shared__ __align__(16) unsigned short At[16 * 264];
  __shared__ int multI[144];
  __shared__ unsigned char srcG[12][12];
  __shared__ unsigned char multG[12][12];
  __shared__ int cntG[12];
  const int bid = blockIdx.x, tid = threadIdx.x;
  const int dir = bid >= NGR;
  const int g = dir ? bid - NGR : bid;
  const int base = g * 12;

  const unsigned short *Pd, *Ps, *gatp;
  unsigned short *Hout;
  int fcol, scol;
  const int* edges;
  if (!dir) {
    Pd = proj_op; Ps = proj_my; fcol = 2048; scol = 2304;
    Hout = Hopp; gatp = gat_op; edges = e_loses;
  } else {
    Pd = proj_my; Ps = proj_op; fcol = 2560; scol = 2816;
    Hout = Hmy; gatp = gat_my; edges = e_rb;
  }

  if (tid < 144) multI[tid] = 0;
  __syncthreads();
  if (tid < 72) {
    const int s = edges[g * 72 + tid] - base;
    const int d = edges[ETOT + g * 72 + tid] - base;
    atomicAdd(&multI[d * 12 + s], 1);
  }
  for (int i = tid; i < 768; i += 256) {
    int s = i >> 6, c4 = (i & 63) * 4;
    const int node = base + s;
    *(ushort4*)&df[s * 256 + c4]  = *(const ushort4*)pnode(Pd, fcol + c4, node);
    *(ushort4*)&dsb[s * 256 + c4] = *(const ushort4*)pnode(Pd, scol + c4, node);
    *(ushort4*)&sfb[s * 256 + c4] = *(const ushort4*)pnode(Ps, fcol + c4, node);
    *(ushort4*)&ssb[s * 256 + c4] = *(const ushort4*)pnode(Ps, scol + c4, node);
  }
  const int c = tid;
  float hv[12], gv[12];
#pragma unroll
  for (int d = 0; d < 12; ++d) {
    const size_t o = (size_t)(base + d) * 256 + c;
    hv[d] = b2f(Hout[o]);
    gv[d] = b2f(gatp[o]);
  }
  __syncthreads();
  if (tid < 12) {
    int n = 0;
    for (int s = 0; s < 12; ++s) {
      const int m = multI[tid * 12 + s];
      if (m > 0) { srcG[tid][n] = (unsigned char)s; multG[tid][n] = (unsigned char)m; ++n; }
    }
    cntG[tid] = n;
  }
  __syncthreads();
  for (int d = 0; d < 12; ++d) {
    const float fd = b2f(df[d * 256 + c]);
    const float sd = b2f(dsb[d * 256 + c]);
    const int n = cntG[d];
    float acc = 0.f;
    for (int j = 0; j < n; ++j) {
      const int s = srcG[d][j];
      const float mlt = (float)multG[d][j];
      const float zf = fd + b2f(sfb[s * 256 + c]);
      const float zs = sd + b2f(ssb[s * 256 + c]);
      const float gate = __builtin_amdgcn_rcpf(1.f + __builtin_amdgcn_exp2f(-LOG2E * zf));
      const float e2 = __builtin_amdgcn_exp2f(-LOG2E * fabsf(zs));
      const float sp = fmaxf(zs, 0.f) + LN2 * __builtin_amdgcn_logf(1.f + e2);
      acc = fmaf(mlt * gate, sp, acc);
    }
    At[d * 264 + c] = f2b(hv[d] + gv[d] + acc);
  }
  __syncthreads();
  {
    const int w = tid >> 6, lane = tid & 63;
    const int r0 = lane & 15, kq = lane >> 4;
#pragma unroll
    for (int n = 0; n < 4; ++n) {
      const unsigned short* wb = node_wtL + ((size_t)(w * 4 + n) * 8) * 512 + lane * 8;
      f32x4 a = (f32x4){0.f, 0.f, 0.f, 0.f};
#pragma unroll
      for (int kt = 0; kt < 8; ++kt) {
        short8 wf = *(const short8*)(wb + kt * 512);
        short8 af = *(const short8*)&At[r0 * 264 + kt * 32 + kq * 8];
        a = __builtin_amdgcn_mfma_f32_16x16x32_bf16(wf, af, a, 0, 0, 0);
      }
      if (r0 < 12) {
        const int col0 = w * 64 + n * 16 + kq * 4;
        const f32x4 bv = *(const f32x4*)&node_bL[col0];
        uint2 pk;
        pk.x = (unsigned)f2b(a[0] + bv[0]) | ((unsigned)f2b(a[1] + bv[1]) << 16);
        pk.y = (unsigned)f2b(a[2] + bv[2]) | ((unsigned)f2b(a[3] + bv[3]) << 16);
        *(uint2*)(Hout + (size_t)(base + r0) * 256 + col0) = pk;
      }
    }
  }
}

// ---------------------------------------------------------------------------
// logits: one wave per node, dot(f[128], W2) + b2
// ---------------------------------------------------------------------------
__global__ __launch_bounds__(256) void logits_kernel(
    const unsigned short* __restrict__ f, const float* __restrict__ W2,
    const float* __restrict__ b2, float* __restrict__ out)
{
  const int node = blockIdx.x * 4 + (threadIdx.x >> 6);
  const int lane = threadIdx.x & 63;
  const size_t o = (size_t)node * 128 + lane * 2;
  float s = b2f(f[o]) * W2[lane * 2] + b2f(f[o + 1]) * W2[lane * 2 + 1];
  for (int d = 32; d > 0; d >>= 1) s += __shfl_down(s, d, 64);
  if (lane == 0) out[node] = s + b2[0];
}

// ---------------------------------------------------------------------------
extern "C" void kernel_launch(void* const* d_in, const int* in_sizes, int n_in,
                              void* d_out, int out_size, void* d_ws, size_t ws_size,
                              hipStream_t stream) {
  const float* x_my    = (const float*)d_in[0];
  const float* x_opp   = (const float*)d_in[1];
  const int*   e_beats = (const int*)d_in[2];
  const int*   e_loses = (const int*)d_in[3];
  const int*   e_rb    = (const int*)d_in[4];
  const int*   e_rl    = (const int*)d_in[5];
  const float* enc_W   = (const float*)d_in[7];
  const float* enc_b   = (const float*)d_in[8];
  const float* gat_Wl  = (const float*)d_in[9];
  const float* gat_bl  = (const float*)d_in[10];
  const float* gat_Wr  = (const float*)d_in[11];
  const float* gat_br  = (const float*)d_in[12];
  const float* gat_att = (const float*)d_in[13];
  const float* gat_bsp = (const float*)d_in[14];
  const float* cg_Wf   = (const float*)d_in[15];
  const float* cg_bf   = (const float*)d_in[16];
  const float* cg_Ws   = (const float*)d_in[17];
  const float* cg_bs   = (const float*)d_in[18];
  const float* node_W  = (const float*)d_in[19];
  const float* node_b  = (const float*)d_in[20];
  const float* fin_W1  = (const float*)d_in[21];
  const float* fin_b1  = (const float*)d_in[22];
  const float* fin_W2  = (const float*)d_in[23];
  const float* fin_b2  = (const float*)d_in[24];

  char* wsp = (char*)d_ws;
  size_t off = 0;
  auto alloc = [&](size_t b) { char* p = wsp + off; off += (b + 255) & ~(size_t)255; return p; };
  unsigned short* wt_my   = (unsigned short*)alloc((size_t)2359296 * 2);
  unsigned short* wt_opp  = (unsigned short*)alloc((size_t)2359296 * 2);
  unsigned short* node_wt = (unsigned short*)alloc((size_t)196608 * 2);
  unsigned short* enc_wt  = (unsigned short*)alloc((size_t)8192 * 2);
  unsigned short* fin_w1t = (unsigned short*)alloc((size_t)32768 * 2);
  float*          bias_my = (float*)alloc((size_t)9216 * 4);
  float*          bias_op = (float*)alloc((size_t)9216 * 4);
  unsigned short* xb      = (unsigned short*)alloc((size_t)786432 * 2);
  unsigned short* Hb      = (unsigned short*)alloc((size_t)2 * NNODES * 256 * 2);
  unsigned short* proj_my = (unsigned short*)alloc((size_t)NNODES * 3072 * 2);
  unsigned short* proj_op = (unsigned short*)alloc((size_t)NNODES * 3072 * 2);
  unsigned short* gat_my  = (unsigned short*)alloc((size_t)NNODES * 256 * 2);
  unsigned short* gat_op  = (unsigned short*)alloc((size_t)NNODES * 256 * 2);
  unsigned short* fbuf    = (unsigned short*)alloc((size_t)NNODES * 128 * 2);

  const int PACK_TOTAL = 2 * 2359296 + 196608 + 8192 + 32768 + 2 * 9216 + 2 * 393216;
  pack_kernel<<<(PACK_TOTAL + 255) / 256, 256, 0, stream>>>(
      gat_Wl, gat_Wr, cg_Wf, cg_Ws, node_W, enc_W, fin_W1,
      gat_bl, gat_br, cg_bf, cg_bs, x_my, x_opp,
      wt_my, wt_opp, node_wt, enc_wt, fin_w1t, bias_my, bias_op, xb);

  unsigned short* Hmy  = Hb;
  unsigned short* Hopp = Hb + (size_t)NNODES * 256;

  // encoder: h = x @ enc_W + enc_b  (M = 24576, N = 256, K = 32)
  gemm64<<<dim3(384, 2), 256, 0, stream>>>(
      xb, xb, 32, enc_wt, enc_wt, enc_b, enc_b, Hb, Hb, 256, 32, 0, 384);

  for (int l = 0; l < 3; ++l) {
    gemm64p<<<dim3(384, 2), 256, 0, stream>>>(
        Hmy, Hopp,
        wt_my + (size_t)l * 786432, wt_opp + (size_t)l * 786432,
        bias_my + l * 3072, bias_op + l * 3072,
        proj_my, proj_op, 192);
    gat_edge<<<2 * NGR, 256, 0, stream>>>(
        proj_my, proj_op, e_beats, e_rl,
        gat_att + l * 2048, gat_bsp + l * 512, gat_op, gat_my);
    cg_fused<<<2 * NGR, 256, 0, stream>>>(
        proj_my, proj_op, Hmy, Hopp, gat_my, gat_op,
        e_loses, e_rb,
        node_wt + (size_t)l * 65536, node_b + l * 256);
  }

  gemm64<<<dim3(192, 1), 256, 0, stream>>>(
      Hmy, Hmy, 256, fin_w1t, fin_w1t, fin_b1, fin_b1, fbuf, fbuf, 128, 256, 1, 192);
  logits_kernel<<<NNODES / 4, 256, 0, stream>>>(fbuf, fin_W2, fin_b2, (float*)d_out);
}

// Round 21
// 456.989 us; speedup vs baseline: 1.0089x; 1.0089x over previous
//
#include <hip/hip_runtime.h>

#define NNODES 12288
#define ETOT   73728
#define NGR    1024
#define LOG2E  1.442695041f
#define LN2    0.6931471806f

typedef __attribute__((ext_vector_type(8))) short short8;
typedef __attribute__((ext_vector_type(4))) float f32x4;

__device__ __forceinline__ unsigned short f2b(float f) {
  return __builtin_bit_cast(unsigned short, (__bf16)f);
}
__device__ __forceinline__ float b2f(unsigned short u) {
  return __uint_as_float(((unsigned)u) << 16);
}
__device__ __forceinline__ void load_lds16(const void* g, void* l) {
  __builtin_amdgcn_global_load_lds(
      (const __attribute__((address_space(1))) unsigned int*)g,
      (__attribute__((address_space(3))) unsigned int*)l, 16, 0, 0);
}
// LDS-only barrier: waits LDS ops, leaves global stores/loads in flight.
__device__ __forceinline__ void lds_barrier() {
  asm volatile("s_waitcnt lgkmcnt(0)" ::: "memory");
  __builtin_amdgcn_s_barrier();
}

// proj layout: [colblk = col>>7][node][col&127]
__device__ __forceinline__ const unsigned short* pnode(
    const unsigned short* P, int col0, int node) {
  return P + ((size_t)(col0 >> 7) * NNODES + node) * 128 + (col0 & 127);
}

// ---------------------------------------------------------------------------
// Pack (unchanged): weights in MFMA-fragment order
// ---------------------------------------------------------------------------
__global__ void pack_kernel(
    const float* __restrict__ gat_Wl, const float* __restrict__ gat_Wr,
    const float* __restrict__ cg_Wf, const float* __restrict__ cg_Ws,
    const float* __restrict__ node_W, const float* __restrict__ enc_W,
    const float* __restrict__ fin_W1,
    const float* __restrict__ gat_bl, const float* __restrict__ gat_br,
    const float* __restrict__ cg_bf, const float* __restrict__ cg_bs,
    const float* __restrict__ x_my, const float* __restrict__ x_opp,
    unsigned short* __restrict__ wt_my, unsigned short* __restrict__ wt_opp,
    unsigned short* __restrict__ node_wt, unsigned short* __restrict__ enc_wt,
    unsigned short* __restrict__ fin_w1t,
    float* __restrict__ bias_my, float* __restrict__ bias_opp,
    unsigned short* __restrict__ xb)
{
  int idx = blockIdx.x * 256 + threadIdx.x;
  if (idx < 2 * 2359296) {
    int which = idx >= 2359296;
    int t = which ? idx - 2359296 : idx;
    int l = t / 786432;
    int r = t - l * 786432;
    int j = r & 7, lane = (r >> 3) & 63, blk = r >> 9;
    int kb = blk & 7, nb = blk >> 3;
    int n = nb * 16 + (lane & 15);
    int k = kb * 32 + (lane >> 4) * 8 + j;
    float v;
    if (!which) {
      if (n < 1024)      v = gat_Wl[((l*2+0)*256 + k)*1024 + n];
      else if (n < 2048) v = gat_Wr[((l*2+1)*256 + k)*1024 + (n-1024)];
      else if (n < 2304) v = cg_Wf[((l*2+0)*512 + 256 + k)*256 + (n-2048)];
      else if (n < 2560) v = cg_Ws[((l*2+0)*512 + 256 + k)*256 + (n-2304)];
      else if (n < 2816) v = cg_Wf[((l*2+1)*512 + k)*256 + (n-2560)];
      else               v = cg_Ws[((l*2+1)*512 + k)*256 + (n-2816)];
      wt_my[t] = f2b(v);
    } else {
      if (n < 1024)      v = gat_Wr[((l*2+0)*256 + k)*1024 + n];
      else if (n < 2048) v = gat_Wl[((l*2+1)*256 + k)*1024 + (n-1024)];
      else if (n < 2304) v = cg_Wf[((l*2+0)*512 + k)*256 + (n-2048)];
      else if (n < 2560) v = cg_Ws[((l*2+0)*512 + k)*256 + (n-2304)];
      else if (n < 2816) v = cg_Wf[((l*2+1)*512 + 256 + k)*256 + (n-2560)];
      else               v = cg_Ws[((l*2+1)*512 + 256 + k)*256 + (n-2816)];
      wt_opp[t] = f2b(v);
    }
    return;
  }
  idx -= 2 * 2359296;
  if (idx < 196608) {
    int l = idx / 65536, r = idx - l * 65536;
    int j = r & 7, lane = (r >> 3) & 63, blk = r >> 9;
    int kb = blk & 7, nb = blk >> 3;
    int n = nb * 16 + (lane & 15);
    int k = kb * 32 + (lane >> 4) * 8 + j;
    node_wt[idx] = f2b(node_W[(l*256 + k)*256 + n]);
    return;
  }
  idx -= 196608;
  if (idx < 8192) {
    int r = idx;
    int j = r & 7, lane = (r >> 3) & 63, blk = r >> 9;
    int nb = blk;
    int n = nb * 16 + (lane & 15);
    int k = (lane >> 4) * 8 + j;
    enc_wt[idx] = f2b(enc_W[k*256 + n]);
    return;
  }
  idx -= 8192;
  if (idx < 32768) {
    int r = idx;
    int j = r & 7, lane = (r >> 3) & 63, blk = r >> 9;
    int kb = blk & 7, nb = blk >> 3;
    int n = nb * 16 + (lane & 15);
    int k = kb * 32 + (lane >> 4) * 8 + j;
    fin_w1t[idx] = f2b(fin_W1[k*128 + n]);
    return;
  }
  idx -= 32768;
  if (idx < 9216) {
    int l = idx / 3072, n = idx - l * 3072;
    float v;
    if (n < 1024)      v = gat_bl[(l*2+0)*1024 + n];
    else if (n < 2048) v = gat_br[(l*2+1)*1024 + (n-1024)];
    else if (n < 2560) v = 0.f;
    else if (n < 2816) v = cg_bf[(l*2+1)*256 + (n-2560)];
    else               v = cg_bs[(l*2+1)*256 + (n-2816)];
    bias_my[idx] = v;
    return;
  }
  idx -= 9216;
  if (idx < 9216) {
    int l = idx / 3072, n = idx - l * 3072;
    float v;
    if (n < 1024)      v = gat_br[(l*2+0)*1024 + n];
    else if (n < 2048) v = gat_bl[(l*2+1)*1024 + (n-1024)];
    else if (n < 2304) v = cg_bf[(l*2+0)*256 + (n-2048)];
    else if (n < 2560) v = cg_bs[(l*2+0)*256 + (n-2304)];
    else               v = 0.f;
    bias_opp[idx] = v;
    return;
  }
  idx -= 9216;
  if (idx < 2 * 393216) {
    xb[idx] = f2b(idx < 393216 ? x_my[idx] : x_opp[idx - 393216]);
  }
}

// ---------------------------------------------------------------------------
// bf16 GEMM v7 (unchanged): used for enc/fin (small-N, row-major out).
// ---------------------------------------------------------------------------
__global__ __launch_bounds__(256) void gemm64(
    const unsigned short* __restrict__ A, const unsigned short* __restrict__ Ab,
    int lda,
    const unsigned short* __restrict__ Wp, const unsigned short* __restrict__ Wpb,
    const float* __restrict__ bias, const float* __restrict__ biasb,
    unsigned short* __restrict__ C, unsigned short* __restrict__ Cb,
    int ldc, int K, int act, int bx_split)
{
  __shared__ __align__(16) unsigned short lA[64 * 256];
  const int tid = threadIdx.x;
  const int lane = tid & 63;
  const int w = tid >> 6;
  const int wr = w >> 1, wc = w & 1;
  const int r0 = lane & 15, kq = lane >> 4;
  const int KT = K >> 5;
  const int gm = (K >> 3) - 1;
  const int rmask = gm > 7 ? 7 : gm;
  const int gsh = __popc((unsigned)gm);

  const unsigned short *Ap, *Wsel;
  const float* bp;
  unsigned short* Cp;
  int tileM;
  if ((int)blockIdx.x < bx_split) {
    Ap = A;  Wsel = Wp;  bp = bias;  Cp = C;  tileM = blockIdx.x * 64;
  } else {
    Ap = Ab; Wsel = Wpb; bp = biasb; Cp = Cb; tileM = (blockIdx.x - bx_split) * 64;
  }
  const int tileN = blockIdx.y * 128;

  for (int rd = 0; rd < KT; ++rd) {
    int idx = rd * 256 + tid;
    int row = idx >> gsh;
    int g = idx & gm;
    load_lds16(Ap + (size_t)(tileM + row) * lda + ((g ^ (row & rmask)) << 3),
               (char*)lA + idx * 16);
  }

  const int nblk0 = (tileN >> 4) + wc * 4;
  const unsigned short* wn0 = Wsel + ((size_t)(nblk0 + 0) * KT * 64 + lane) * 8;
  const unsigned short* wn1 = Wsel + ((size_t)(nblk0 + 1) * KT * 64 + lane) * 8;
  const unsigned short* wn2 = Wsel + ((size_t)(nblk0 + 2) * KT * 64 + lane) * 8;
  const unsigned short* wn3 = Wsel + ((size_t)(nblk0 + 3) * KT * 64 + lane) * 8;

  short8 b0_0 = *(const short8*)wn0;
  short8 b0_1 = *(const short8*)wn1;
  short8 b0_2 = *(const short8*)wn2;
  short8 b0_3 = *(const short8*)wn3;
  short8 b1_0 = b0_0, b1_1 = b0_1, b1_2 = b0_2, b1_3 = b0_3;
  if (KT > 1) {
    b1_0 = *(const short8*)(wn0 + 512);
    b1_1 = *(const short8*)(wn1 + 512);
    b1_2 = *(const short8*)(wn2 + 512);
    b1_3 = *(const short8*)(wn3 + 512);
  }

  f32x4 acc[2][4];
#pragma unroll
  for (int m = 0; m < 2; ++m)
#pragma unroll
    for (int n = 0; n < 4; ++n)
      acc[m][n] = (f32x4){0.f, 0.f, 0.f, 0.f};

  const int rb0 = (wr * 32 + r0) * K;
  const int rb1 = (wr * 32 + 16 + r0) * K;
  const int rx = r0 & rmask;

  __syncthreads();

  for (int kt = 0; kt < KT; ++kt) {
    short8 b2_0 = b1_0, b2_1 = b1_1, b2_2 = b1_2, b2_3 = b1_3;
    if (kt + 2 < KT) {
      const int o = (kt + 2) * 512;
      b2_0 = *(const short8*)(wn0 + o);
      b2_1 = *(const short8*)(wn1 + o);
      b2_2 = *(const short8*)(wn2 + o);
      b2_3 = *(const short8*)(wn3 + o);
    }
    const int p = (((kt << 2) + kq) ^ rx) * 8;
    short8 af0 = *(const short8*)&lA[rb0 + p];
    short8 af1 = *(const short8*)&lA[rb1 + p];
    acc[0][0] = __builtin_amdgcn_mfma_f32_16x16x32_bf16(b0_0, af0, acc[0][0], 0, 0, 0);
    acc[0][1] = __builtin_amdgcn_mfma_f32_16x16x32_bf16(b0_1, af0, acc[0][1], 0, 0, 0);
    acc[0][2] = __builtin_amdgcn_mfma_f32_16x16x32_bf16(b0_2, af0, acc[0][2], 0, 0, 0);
    acc[0][3] = __builtin_amdgcn_mfma_f32_16x16x32_bf16(b0_3, af0, acc[0][3], 0, 0, 0);
    acc[1][0] = __builtin_amdgcn_mfma_f32_16x16x32_bf16(b0_0, af1, acc[1][0], 0, 0, 0);
    acc[1][1] = __builtin_amdgcn_mfma_f32_16x16x32_bf16(b0_1, af1, acc[1][1], 0, 0, 0);
    acc[1][2] = __builtin_amdgcn_mfma_f32_16x16x32_bf16(b0_2, af1, acc[1][2], 0, 0, 0);
    acc[1][3] = __builtin_amdgcn_mfma_f32_16x16x32_bf16(b0_3, af1, acc[1][3], 0, 0, 0);
    b0_0 = b1_0; b0_1 = b1_1; b0_2 = b1_2; b0_3 = b1_3;
    b1_0 = b2_0; b1_1 = b2_1; b1_2 = b2_2; b1_3 = b2_3;
  }

  unsigned short* cT = lA;
  __syncthreads();
#pragma unroll
  for (int m = 0; m < 2; ++m) {
    const int rl = wr * 32 + m * 16 + r0;
#pragma unroll
    for (int n = 0; n < 4; ++n) {
      const int cl = wc * 64 + n * 16 + kq * 4;
      const f32x4 bv = *(const f32x4*)&bp[tileN + cl];
      float v0 = acc[m][n][0] + bv[0];
      float v1 = acc[m][n][1] + bv[1];
      float v2 = acc[m][n][2] + bv[2];
      float v3 = acc[m][n][3] + bv[3];
      if (act) {
        v0 = v0 > 0.f ? v0 : 128.f * v0;
        v1 = v1 > 0.f ? v1 : 128.f * v1;
        v2 = v2 > 0.f ? v2 : 128.f * v2;
        v3 = v3 > 0.f ? v3 : 128.f * v3;
      }
      uint2 pk;
      pk.x = (unsigned)f2b(v0) | ((unsigned)f2b(v1) << 16);
      pk.y = (unsigned)f2b(v2) | ((unsigned)f2b(v3) << 16);
      *(uint2*)&cT[rl * 132 + cl] = pk;
    }
  }
  __syncthreads();
#pragma unroll
  for (int it = 0; it < 4; ++it) {
    const int idx = it * 256 + tid;
    const int row = idx >> 4, ch = idx & 15;
    const uint4 val = *(const uint4*)&cT[row * 132 + ch * 8];
    *(uint4*)(Cp + (size_t)(tileM + row) * ldc + tileN + ch * 8) = val;
  }
}

// ---------------------------------------------------------------------------
// gemm64p v3: persistent-A proj GEMM, XCD-TYPE-PARTITIONED: blocks whose
// XCD (= bx & 7, round-robin dispatch) is 0-3 handle `my`, 4-7 handle `opp`,
// so each per-XCD L2 holds only ONE 3MB weight image (fits 4MiB) -> W stays
// L2-resident, B-fragment loads are L2 hits. Bijective tile mapping:
// idx = (bx>>3)*4 + (bx&3). LDS-only barriers in the nn loop.
// ---------------------------------------------------------------------------
__global__ __launch_bounds__(256) void gemm64p(
    const unsigned short* __restrict__ A, const unsigned short* __restrict__ Ab,
    const unsigned short* __restrict__ Wp, const unsigned short* __restrict__ Wpb,
    const float* __restrict__ bias, const float* __restrict__ biasb,
    unsigned short* __restrict__ C, unsigned short* __restrict__ Cb)
{
  const int K = 256, KT = 8;
  __shared__ __align__(16) unsigned short lA[64 * 256];
  __shared__ __align__(16) unsigned short cT[64 * 132];
  const int tid = threadIdx.x;
  const int lane = tid & 63;
  const int w = tid >> 6;
  const int wr = w >> 1, wc = w & 1;
  const int r0 = lane & 15, kq = lane >> 4;

  const int bx = (int)blockIdx.x;
  const int isopp = (bx & 4) >> 2;            // XCD 0-3 -> my, 4-7 -> opp
  const int idxm = (bx >> 3) * 4 + (bx & 3);  // 0..191 within type

  const unsigned short *Ap, *Wsel;
  const float* bp;
  unsigned short* Cp;
  if (!isopp) { Ap = A;  Wsel = Wp;  bp = bias;  Cp = C;  }
  else        { Ap = Ab; Wsel = Wpb; bp = biasb; Cp = Cb; }
  const int tileM = idxm * 64;

  for (int rd = 0; rd < KT; ++rd) {
    int idx = rd * 256 + tid;
    int row = idx >> 5;
    int g = idx & 31;
    load_lds16(Ap + (size_t)(tileM + row) * K + ((g ^ (row & 7)) << 3),
               (char*)lA + idx * 16);
  }

  const int rb0 = (wr * 32 + r0) * K;
  const int rb1 = (wr * 32 + 16 + r0) * K;
  const int rx = r0 & 7;

  __syncthreads();   // A tile resident (global_load_lds needs full drain)

  for (int nn = 0; nn < 12; ++nn) {
    const int cb = (int)blockIdx.y * 12 + nn;
    const int tileN = cb * 128;
    const int nblk0 = (tileN >> 4) + wc * 4;
    const unsigned short* wn0 = Wsel + ((size_t)(nblk0 + 0) * KT * 64 + lane) * 8;
    const unsigned short* wn1 = Wsel + ((size_t)(nblk0 + 1) * KT * 64 + lane) * 8;
    const unsigned short* wn2 = Wsel + ((size_t)(nblk0 + 2) * KT * 64 + lane) * 8;
    const unsigned short* wn3 = Wsel + ((size_t)(nblk0 + 3) * KT * 64 + lane) * 8;

    short8 b0_0 = *(const short8*)wn0;
    short8 b0_1 = *(const short8*)wn1;
    short8 b0_2 = *(const short8*)wn2;
    short8 b0_3 = *(const short8*)wn3;
    short8 b1_0 = *(const short8*)(wn0 + 512);
    short8 b1_1 = *(const short8*)(wn1 + 512);
    short8 b1_2 = *(const short8*)(wn2 + 512);
    short8 b1_3 = *(const short8*)(wn3 + 512);

    f32x4 acc[2][4];
#pragma unroll
    for (int m = 0; m < 2; ++m)
#pragma unroll
      for (int n = 0; n < 4; ++n)
        acc[m][n] = (f32x4){0.f, 0.f, 0.f, 0.f};

    for (int kt = 0; kt < KT; ++kt) {
      short8 b2_0 = b1_0, b2_1 = b1_1, b2_2 = b1_2, b2_3 = b1_3;
      if (kt + 2 < KT) {
        const int o = (kt + 2) * 512;
        b2_0 = *(const short8*)(wn0 + o);
        b2_1 = *(const short8*)(wn1 + o);
        b2_2 = *(const short8*)(wn2 + o);
        b2_3 = *(const short8*)(wn3 + o);
      }
      const int p = (((kt << 2) + kq) ^ rx) * 8;
      short8 af0 = *(const short8*)&lA[rb0 + p];
      short8 af1 = *(const short8*)&lA[rb1 + p];
      acc[0][0] = __builtin_amdgcn_mfma_f32_16x16x32_bf16(b0_0, af0, acc[0][0], 0, 0, 0);
      acc[0][1] = __builtin_amdgcn_mfma_f32_16x16x32_bf16(b0_1, af0, acc[0][1], 0, 0, 0);
      acc[0][2] = __builtin_amdgcn_mfma_f32_16x16x32_bf16(b0_2, af0, acc[0][2], 0, 0, 0);
      acc[0][3] = __builtin_amdgcn_mfma_f32_16x16x32_bf16(b0_3, af0, acc[0][3], 0, 0, 0);
      acc[1][0] = __builtin_amdgcn_mfma_f32_16x16x32_bf16(b0_0, af1, acc[1][0], 0, 0, 0);
      acc[1][1] = __builtin_amdgcn_mfma_f32_16x16x32_bf16(b0_1, af1, acc[1][1], 0, 0, 0);
      acc[1][2] = __builtin_amdgcn_mfma_f32_16x16x32_bf16(b0_2, af1, acc[1][2], 0, 0, 0);
      acc[1][3] = __builtin_amdgcn_mfma_f32_16x16x32_bf16(b0_3, af1, acc[1][3], 0, 0, 0);
      b0_0 = b1_0; b0_1 = b1_1; b0_2 = b1_2; b0_3 = b1_3;
      b1_0 = b2_0; b1_1 = b2_1; b1_2 = b2_2; b1_3 = b2_3;
    }

    lds_barrier();   // prior nn's cT reads complete (LDS-only)
#pragma unroll
    for (int m = 0; m < 2; ++m) {
      const int rl = wr * 32 + m * 16 + r0;
#pragma unroll
      for (int n = 0; n < 4; ++n) {
        const int cl = wc * 64 + n * 16 + kq * 4;
        const f32x4 bv = *(const f32x4*)&bp[tileN + cl];
        uint2 pk;
        pk.x = (unsigned)f2b(acc[m][n][0] + bv[0]) |
               ((unsigned)f2b(acc[m][n][1] + bv[1]) << 16);
        pk.y = (unsigned)f2b(acc[m][n][2] + bv[2]) |
               ((unsigned)f2b(acc[m][n][3] + bv[3]) << 16);
        *(uint2*)&cT[rl * 132 + cl] = pk;
      }
    }
    lds_barrier();   // cT writes visible (LDS-only)
    unsigned short* dstb = Cp + ((size_t)cb * NNODES + tileM) * 128;
#pragma unroll
    for (int it = 0; it < 4; ++it) {
      const int idx = it * 256 + tid;
      const uint4 val = *(const uint4*)&cT[(idx >> 4) * 132 + (idx & 15) * 8];
      *(uint4*)(dstb + (size_t)idx * 8) = val;
    }
  }
}

// ---------------------------------------------------------------------------
// GATv2 edge stage v10 (unchanged): group-per-(d,h), shuffle softmax.
// ---------------------------------------------------------------------------
#define SX 260
__global__ __launch_bounds__(256) void gat_edge(
    const unsigned short* __restrict__ proj_my,
    const unsigned short* __restrict__ proj_op,
    const int* __restrict__ e_beats, const int* __restrict__ e_rl,
    const float* __restrict__ attL, const float* __restrict__ gbiasL,
    unsigned short* __restrict__ gat_op, unsigned short* __restrict__ gat_my)
{
  __shared__ __align__(16) unsigned short xl[48 * SX];
  __shared__ __align__(16) float attS[4 * SX];
  __shared__ __align__(16) float A2f[12 * 48];
  __shared__ int multI[144];
  __shared__ unsigned char srcG[12][12];
  __shared__ unsigned char multG[12][12];
  __shared__ int cntG[12];
  const int bid = blockIdx.x, tid = threadIdx.x;
  const int dir = bid >= NGR;
  const int g = dir ? bid - NGR : bid;
  const int base = g * 12;

  const unsigned short *Psrc, *Pdst;
  int pcol0;
  const int* edges;
  const float* att;
  const float* gbias;
  unsigned short* outp;
  if (!dir) {
    Psrc = proj_my; Pdst = proj_op; pcol0 = 0;
    edges = e_beats; att = attL; gbias = gbiasL; outp = gat_op;
  } else {
    Psrc = proj_op; Pdst = proj_my; pcol0 = 1024;
    edges = e_rl; att = attL + 1024; gbias = gbiasL + 256; outp = gat_my;
  }

  if (tid < 144) multI[tid] = 0;
  for (int i = tid; i < 576; i += 256) A2f[i] = 0.f;
  __syncthreads();
  if (tid < 72) {
    const int s = edges[g * 72 + tid] - base;
    const int d = edges[ETOT + g * 72 + tid] - base;
    atomicAdd(&multI[d * 12 + s], 1);
  }
  for (int i = tid; i < 1024; i += 256)
    attS[(i >> 8) * SX + (i & 255)] = att[i];
  for (int i = tid; i < 3072; i += 256) {
    int s = i >> 8, c4 = (i & 255) * 4;
    int h = c4 >> 8, cc = c4 & 255;
    *(ushort4*)&xl[(h * 12 + s) * SX + cc] =
        *(const ushort4*)pnode(Psrc, pcol0 + c4, base + s);
  }
  __syncthreads();

  if (tid < 12) {
    int n = 0;
    for (int s = 0; s < 12; ++s) {
      const int m = multI[tid * 12 + s];
      if (m > 0) { srcG[tid][n] = (unsigned char)s; multG[tid][n] = (unsigned char)m; ++n; }
    }
    cntG[tid] = n;
  }
  __syncthreads();

  for (int r = 0; r < 3; ++r) {
    const int slot = r * 256 + tid;
    const int g16 = slot >> 4, lane16 = slot & 15;
    const int d = g16 >> 2, h = g16 & 3;
    const int cnt = cntG[d];
    const int ch0 = lane16 * 16;
    const unsigned short* prp = pnode(Pdst, pcol0 + h * 256 + ch0, base + d);
    const ushort4 xr0 = *(const ushort4*)(prp);
    const ushort4 xr1 = *(const ushort4*)(prp + 4);
    const ushort4 xr2 = *(const ushort4*)(prp + 8);
    const ushort4 xr3 = *(const ushort4*)(prp + 12);
    const float* pa = &attS[h * SX + ch0];
    const f32x4 at0 = *(const f32x4*)(pa);
    const f32x4 at1 = *(const f32x4*)(pa + 4);
    const f32x4 at2 = *(const f32x4*)(pa + 8);
    const f32x4 at3 = *(const f32x4*)(pa + 12);

    float myalpha = -1e30f;
    for (int j = 0; j < cnt; ++j) {
      const int s = srcG[d][j];
      const unsigned short* pl = &xl[(h * 12 + s) * SX + ch0];
      float p = 0.f;
      {
        ushort4 a4 = *(const ushort4*)(pl);
        float v0 = b2f(a4.x) + b2f(xr0.x); v0 = fmaxf(v0, 0.2f * v0);
        float v1 = b2f(a4.y) + b2f(xr0.y); v1 = fmaxf(v1, 0.2f * v1);
        float v2 = b2f(a4.z) + b2f(xr0.z); v2 = fmaxf(v2, 0.2f * v2);
        float v3 = b2f(a4.w) + b2f(xr0.w); v3 = fmaxf(v3, 0.2f * v3);
        p = fmaf(v0, at0[0], p); p = fmaf(v1, at0[1], p);
        p = fmaf(v2, at0[2], p); p = fmaf(v3, at0[3], p);
      }
      {
        ushort4 a4 = *(const ushort4*)(pl + 4);
        float v0 = b2f(a4.x) + b2f(xr1.x); v0 = fmaxf(v0, 0.2f * v0);
        float v1 = b2f(a4.y) + b2f(xr1.y); v1 = fmaxf(v1, 0.2f * v1);
        float v2 = b2f(a4.z) + b2f(xr1.z); v2 = fmaxf(v2, 0.2f * v2);
        float v3 = b2f(a4.w) + b2f(xr1.w); v3 = fmaxf(v3, 0.2f * v3);
        p = fmaf(v0, at1[0], p); p = fmaf(v1, at1[1], p);
        p = fmaf(v2, at1[2], p); p = fmaf(v3, at1[3], p);
      }
      {
        ushort4 a4 = *(const ushort4*)(pl + 8);
        float v0 = b2f(a4.x) + b2f(xr2.x); v0 = fmaxf(v0, 0.2f * v0);
        float v1 = b2f(a4.y) + b2f(xr2.y); v1 = fmaxf(v1, 0.2f * v1);
        float v2 = b2f(a4.z) + b2f(xr2.z); v2 = fmaxf(v2, 0.2f * v2);
        float v3 = b2f(a4.w) + b2f(xr2.w); v3 = fmaxf(v3, 0.2f * v3);
        p = fmaf(v0, at2[0], p); p = fmaf(v1, at2[1], p);
        p = fmaf(v2, at2[2], p); p = fmaf(v3, at2[3], p);
      }
      {
        ushort4 a4 = *(const ushort4*)(pl + 12);
        float v0 = b2f(a4.x) + b2f(xr3.x); v0 = fmaxf(v0, 0.2f * v0);
        float v1 = b2f(a4.y) + b2f(xr3.y); v1 = fmaxf(v1, 0.2f * v1);
        float v2 = b2f(a4.z) + b2f(xr3.z); v2 = fmaxf(v2, 0.2f * v2);
        float v3 = b2f(a4.w) + b2f(xr3.w); v3 = fmaxf(v3, 0.2f * v3);
        p = fmaf(v0, at3[0], p); p = fmaf(v1, at3[1], p);
        p = fmaf(v2, at3[2], p); p = fmaf(v3, at3[3], p);
      }
#pragma unroll
      for (int off = 1; off < 16; off <<= 1) p += __shfl_xor(p, off, 64);
      if (j == lane16) myalpha = p * LOG2E;
    }
    float m = myalpha;
#pragma unroll
    for (int off = 1; off < 16; off <<= 1) m = fmaxf(m, __shfl_xor(m, off, 64));
    const float wv = __builtin_amdgcn_exp2f(myalpha - m);
    const float mw = (lane16 < cnt) ? (float)multG[d][lane16] * wv : 0.f;
    float den = mw;
#pragma unroll
    for (int off = 1; off < 16; off <<= 1) den += __shfl_xor(den, off, 64);
    const float inv = 0.25f * __builtin_amdgcn_rcpf(den + 1e-16f);
    if (lane16 < cnt) A2f[d * 48 + h * 12 + srcG[d][lane16]] = mw * inv;
  }
  __syncthreads();

  {
    const int c = tid;
    float xlv[48];
#pragma unroll
    for (int j = 0; j < 48; ++j) xlv[j] = b2f(xl[j * SX + c]);
    const float gb = gbias[c];
#pragma unroll
    for (int d = 0; d < 12; ++d) {
      const f32x4* arow = (const f32x4*)&A2f[d * 48];
      float s = 0.f;
#pragma unroll
      for (int jj = 0; jj < 12; ++jj) {
        f32x4 a4 = arow[jj];
        s = fmaf(a4.x, xlv[jj * 4 + 0], s);
        s = fmaf(a4.y, xlv[jj * 4 + 1], s);
        s = fmaf(a4.z, xlv[jj * 4 + 2], s);
        s = fmaf(a4.w, xlv[jj * 4 + 3], s);
      }
      outp[(size_t)(base + d) * 256 + c] = f2b(s + gb);
    }
  }
}

// ---------------------------------------------------------------------------
// cg_fused v2 (unchanged): dedup'd CGConv combine + node MFMA.
// ---------------------------------------------------------------------------
__global__ __launch_bounds__(256) void cg_fused(
    const unsigned short* __restrict__ proj_my,
    const unsigned short* __restrict__ proj_op,
    unsigned short* __restrict__ Hmy, unsigned short* __restrict__ Hopp,
    const unsigned short* __restrict__ gat_my, const unsigned short* __restrict__ gat_op,
    const int* __restrict__ e_loses, const int* __restrict__ e_rb,
    const unsigned short* __restrict__ node_wtL, const float* __restrict__ node_bL)
{
  __shared__ __align__(8) unsigned short df[3072], dsb[3072];
  __shared__ __align__(8) unsigned short sfb[3072], ssb[3072];
  __shared__ __align__(16) unsigned short At[16 * 264];
  __shared__ int multI[144];
  __shared__ unsigned char srcG[12][12];
  __shared__ unsigned char multG[12][12];
  __shared__ int cntG[12];
  const int bid = blockIdx.x, tid = threadIdx.x;
  const int dir = bid >= NGR;
  const int g = dir ? bid - NGR : bid;
  const int base = g * 12;

  const unsigned short *Pd, *Ps, *gatp;
  unsigned short *Hout;
  int fcol, scol;
  const int* edges;
  if (!dir) {
    Pd = proj_op; Ps = proj_my; fcol = 2048; scol = 2304;
    Hout = Hopp; gatp = gat_op; edges = e_loses;
  } else {
    Pd = proj_my; Ps = proj_op; fcol = 2560; scol = 2816;
    Hout = Hmy; gatp = gat_my; edges = e_rb;
  }

  if (tid < 144) multI[tid] = 0;
  __syncthreads();
  if (tid < 72) {
    const int s = edges[g * 72 + tid] - base;
    const int d = edges[ETOT + g * 72 + tid] - base;
    atomicAdd(&multI[d * 12 + s], 1);
  }
  for (int i = tid; i < 768; i += 256) {
    int s = i >> 6, c4 = (i & 63) * 4;
    const int node = base + s;
    *(ushort4*)&df[s * 256 + c4]  = *(const ushort4*)pnode(Pd, fcol + c4, node);
    *(ushort4*)&dsb[s * 256 + c4] = *(const ushort4*)pnode(Pd, scol + c4, node);
    *(ushort4*)&sfb[s * 256 + c4] = *(const ushort4*)pnode(Ps, fcol + c4, node);
    *(ushort4*)&ssb[s * 256 + c4] = *(const ushort4*)pnode(Ps, scol + c4, node);
  }
  const int c = tid;
  float hv[12], gv[12];
#pragma unroll
  for (int d = 0; d < 12; ++d) {
    const size_t o = (size_t)(base + d) * 256 + c;
    hv[d] = b2f(Hout[o]);
    gv[d] = b2f(gatp[o]);
  }
  __syncthreads();
  if (tid < 12) {
    int n = 0;
    for (int s = 0; s < 12; ++s) {
      const int m = multI[tid * 12 + s];
      if (m > 0) { srcG[tid][n] = (unsigned char)s; multG[tid][n] = (unsigned char)m; ++n; }
    }
    cntG[tid] = n;
  }
  __syncthreads();
  for (int d = 0; d < 12; ++d) {
    const float fd = b2f(df[d * 256 + c]);
    const float sd = b2f(dsb[d * 256 + c]);
    const int n = cntG[d];
    float acc = 0.f;
    for (int j = 0; j < n; ++j) {
      const int s = srcG[d][j];
      const float mlt = (float)multG[d][j];
      const float zf = fd + b2f(sfb[s * 256 + c]);
      const float zs = sd + b2f(ssb[s * 256 + c]);
      const float gate = __builtin_amdgcn_rcpf(1.f + __builtin_amdgcn_exp2f(-LOG2E * zf));
      const float e2 = __builtin_amdgcn_exp2f(-LOG2E * fabsf(zs));
      const float sp = fmaxf(zs, 0.f) + LN2 * __builtin_amdgcn_logf(1.f + e2);
      acc = fmaf(mlt * gate, sp, acc);
    }
    At[d * 264 + c] = f2b(hv[d] + gv[d] + acc);
  }
  __syncthreads();
  {
    const int w = tid >> 6, lane = tid & 63;
    const int r0 = lane & 15, kq = lane >> 4;
#pragma unroll
    for (int n = 0; n < 4; ++n) {
      const unsigned short* wb = node_wtL + ((size_t)(w * 4 + n) * 8) * 512 + lane * 8;
      f32x4 a = (f32x4){0.f, 0.f, 0.f, 0.f};
#pragma unroll
      for (int kt = 0; kt < 8; ++kt) {
        short8 wf = *(const short8*)(wb + kt * 512);
        short8 af = *(const short8*)&At[r0 * 264 + kt * 32 + kq * 8];
        a = __builtin_amdgcn_mfma_f32_16x16x32_bf16(wf, af, a, 0, 0, 0);
      }
      if (r0 < 12) {
        const int col0 = w * 64 + n * 16 + kq * 4;
        const f32x4 bv = *(const f32x4*)&node_bL[col0];
        uint2 pk;
        pk.x = (unsigned)f2b(a[0] + bv[0]) | ((unsigned)f2b(a[1] + bv[1]) << 16);
        pk.y = (unsigned)f2b(a[2] + bv[2]) | ((unsigned)f2b(a[3] + bv[3]) << 16);
        *(uint2*)(Hout + (size_t)(base + r0) * 256 + col0) = pk;
      }
    }
  }
}

// ---------------------------------------------------------------------------
// logits: one wave per node, dot(f[128], W2) + b2
// ---------------------------------------------------------------------------
__global__ __launch_bounds__(256) void logits_kernel(
    const unsigned short* __restrict__ f, const float* __restrict__ W2,
    const float* __restrict__ b2, float* __restrict__ out)
{
  const int node = blockIdx.x * 4 + (threadIdx.x >> 6);
  const int lane = threadIdx.x & 63;
  const size_t o = (size_t)node * 128 + lane * 2;
  float s = b2f(f[o]) * W2[lane * 2] + b2f(f[o + 1]) * W2[lane * 2 + 1];
  for (int d = 32; d > 0; d >>= 1) s += __shfl_down(s, d, 64);
  if (lane == 0) out[node] = s + b2[0];
}

// ---------------------------------------------------------------------------
extern "C" void kernel_launch(void* const* d_in, const int* in_sizes, int n_in,
                              void* d_out, int out_size, void* d_ws, size_t ws_size,
                              hipStream_t stream) {
  const float* x_my    = (const float*)d_in[0];
  const float* x_opp   = (const float*)d_in[1];
  const int*   e_beats = (const int*)d_in[2];
  const int*   e_loses = (const int*)d_in[3];
  const int*   e_rb    = (const int*)d_in[4];
  const int*   e_rl    = (const int*)d_in[5];
  const float* enc_W   = (const float*)d_in[7];
  const float* enc_b   = (const float*)d_in[8];
  const float* gat_Wl  = (const float*)d_in[9];
  const float* gat_bl  = (const float*)d_in[10];
  const float* gat_Wr  = (const float*)d_in[11];
  const float* gat_br  = (const float*)d_in[12];
  const float* gat_att = (const float*)d_in[13];
  const float* gat_bsp = (const float*)d_in[14];
  const float* cg_Wf   = (const float*)d_in[15];
  const float* cg_bf   = (const float*)d_in[16];
  const float* cg_Ws   = (const float*)d_in[17];
  const float* cg_bs   = (const float*)d_in[18];
  const float* node_W  = (const float*)d_in[19];
  const float* node_b  = (const float*)d_in[20];
  const float* fin_W1  = (const float*)d_in[21];
  const float* fin_b1  = (const float*)d_in[22];
  const float* fin_W2  = (const float*)d_in[23];
  const float* fin_b2  = (const float*)d_in[24];

  char* wsp = (char*)d_ws;
  size_t off = 0;
  auto alloc = [&](size_t b) { char* p = wsp + off; off += (b + 255) & ~(size_t)255; return p; };
  unsigned short* wt_my   = (unsigned short*)alloc((size_t)2359296 * 2);
  unsigned short* wt_opp  = (unsigned short*)alloc((size_t)2359296 * 2);
  unsigned short* node_wt = (unsigned short*)alloc((size_t)196608 * 2);
  unsigned short* enc_wt  = (unsigned short*)alloc((size_t)8192 * 2);
  unsigned short* fin_w1t = (unsigned short*)alloc((size_t)32768 * 2);
  float*          bias_my = (float*)alloc((size_t)9216 * 4);
  float*          bias_op = (float*)alloc((size_t)9216 * 4);
  unsigned short* xb      = (unsigned short*)alloc((size_t)786432 * 2);
  unsigned short* Hb      = (unsigned short*)alloc((size_t)2 * NNODES * 256 * 2);
  unsigned short* proj_my = (unsigned short*)alloc((size_t)NNODES * 3072 * 2);
  unsigned short* proj_op = (unsigned short*)alloc((size_t)NNODES * 3072 * 2);
  unsigned short* gat_my  = (unsigned short*)alloc((size_t)NNODES * 256 * 2);
  unsigned short* gat_op  = (unsigned short*)alloc((size_t)NNODES * 256 * 2);
  unsigned short* fbuf    = (unsigned short*)alloc((size_t)NNODES * 128 * 2);

  const int PACK_TOTAL = 2 * 2359296 + 196608 + 8192 + 32768 + 2 * 9216 + 2 * 393216;
  pack_kernel<<<(PACK_TOTAL + 255) / 256, 256, 0, stream>>>(
      gat_Wl, gat_Wr, cg_Wf, cg_Ws, node_W, enc_W, fin_W1,
      gat_bl, gat_br, cg_bf, cg_bs, x_my, x_opp,
      wt_my, wt_opp, node_wt, enc_wt, fin_w1t, bias_my, bias_op, xb);

  unsigned short* Hmy  = Hb;
  unsigned short* Hopp = Hb + (size_t)NNODES * 256;

  // encoder: h = x @ enc_W + enc_b  (M = 24576, N = 256, K = 32)
  gemm64<<<dim3(384, 2), 256, 0, stream>>>(
      xb, xb, 32, enc_wt, enc_wt, enc_b, enc_b, Hb, Hb, 256, 32, 0, 384);

  for (int l = 0; l < 3; ++l) {
    gemm64p<<<dim3(384, 2), 256, 0, stream>>>(
        Hmy, Hopp,
        wt_my + (size_t)l * 786432, wt_opp + (size_t)l * 786432,
        bias_my + l * 3072, bias_op + l * 3072,
        proj_my, proj_op);
    gat_edge<<<2 * NGR, 256, 0, stream>>>(
        proj_my, proj_op, e_beats, e_rl,
        gat_att + l * 2048, gat_bsp + l * 512, gat_op, gat_my);
    cg_fused<<<2 * NGR, 256, 0, stream>>>(
        proj_my, proj_op, Hmy, Hopp, gat_my, gat_op,
        e_loses, e_rb,
        node_wt + (size_t)l * 65536, node_b + l * 256);
  }

  gemm64<<<dim3(192, 1), 256, 0, stream>>>(
      Hmy, Hmy, 256, fin_w1t, fin_w1t, fin_b1, fin_b1, fbuf, fbuf, 128, 256, 1, 192);
  logits_kernel<<<NNODES / 4, 256, 0, stream>>>(fbuf, fin_W2, fin_b2, (float*)d_out);
}

// Round 22
// 456.923 us; speedup vs baseline: 1.0090x; 1.0001x over previous
//
#include <hip/hip_runtime.h>

#define NNODES 12288
#define ETOT   73728
#define NGR    1024
#define LOG2E  1.442695041f
#define LN2    0.6931471806f

typedef __attribute__((ext_vector_type(8))) short short8;
typedef __attribute__((ext_vector_type(4))) float f32x4;

__device__ __forceinline__ unsigned short f2b(float f) {
  return __builtin_bit_cast(unsigned short, (__bf16)f);
}
__device__ __forceinline__ float b2f(unsigned short u) {
  return __uint_as_float(((unsigned)u) << 16);
}
__device__ __forceinline__ void load_lds16(const void* g, void* l) {
  __builtin_amdgcn_global_load_lds(
      (const __attribute__((address_space(1))) unsigned int*)g,
      (__attribute__((address_space(3))) unsigned int*)l, 16, 0, 0);
}
// LDS-only barrier: waits LDS ops, leaves global stores/loads in flight.
__device__ __forceinline__ void lds_barrier() {
  asm volatile("s_waitcnt lgkmcnt(0)" ::: "memory");
  __builtin_amdgcn_s_barrier();
}

// proj layout: [colblk = col>>7][node][col&127]
__device__ __forceinline__ const unsigned short* pnode(
    const unsigned short* P, int col0, int node) {
  return P + ((size_t)(col0 >> 7) * NNODES + node) * 128 + (col0 & 127);
}

// ---------------------------------------------------------------------------
// Pack (unchanged): weights in MFMA-fragment order
// ---------------------------------------------------------------------------
__global__ void pack_kernel(
    const float* __restrict__ gat_Wl, const float* __restrict__ gat_Wr,
    const float* __restrict__ cg_Wf, const float* __restrict__ cg_Ws,
    const float* __restrict__ node_W, const float* __restrict__ enc_W,
    const float* __restrict__ fin_W1,
    const float* __restrict__ gat_bl, const float* __restrict__ gat_br,
    const float* __restrict__ cg_bf, const float* __restrict__ cg_bs,
    const float* __restrict__ x_my, const float* __restrict__ x_opp,
    unsigned short* __restrict__ wt_my, unsigned short* __restrict__ wt_opp,
    unsigned short* __restrict__ node_wt, unsigned short* __restrict__ enc_wt,
    unsigned short* __restrict__ fin_w1t,
    float* __restrict__ bias_my, float* __restrict__ bias_opp,
    unsigned short* __restrict__ xb)
{
  int idx = blockIdx.x * 256 + threadIdx.x;
  if (idx < 2 * 2359296) {
    int which = idx >= 2359296;
    int t = which ? idx - 2359296 : idx;
    int l = t / 786432;
    int r = t - l * 786432;
    int j = r & 7, lane = (r >> 3) & 63, blk = r >> 9;
    int kb = blk & 7, nb = blk >> 3;
    int n = nb * 16 + (lane & 15);
    int k = kb * 32 + (lane >> 4) * 8 + j;
    float v;
    if (!which) {
      if (n < 1024)      v = gat_Wl[((l*2+0)*256 + k)*1024 + n];
      else if (n < 2048) v = gat_Wr[((l*2+1)*256 + k)*1024 + (n-1024)];
      else if (n < 2304) v = cg_Wf[((l*2+0)*512 + 256 + k)*256 + (n-2048)];
      else if (n < 2560) v = cg_Ws[((l*2+0)*512 + 256 + k)*256 + (n-2304)];
      else if (n < 2816) v = cg_Wf[((l*2+1)*512 + k)*256 + (n-2560)];
      else               v = cg_Ws[((l*2+1)*512 + k)*256 + (n-2816)];
      wt_my[t] = f2b(v);
    } else {
      if (n < 1024)      v = gat_Wr[((l*2+0)*256 + k)*1024 + n];
      else if (n < 2048) v = gat_Wl[((l*2+1)*256 + k)*1024 + (n-1024)];
      else if (n < 2304) v = cg_Wf[((l*2+0)*512 + k)*256 + (n-2048)];
      else if (n < 2560) v = cg_Ws[((l*2+0)*512 + k)*256 + (n-2304)];
      else if (n < 2816) v = cg_Wf[((l*2+1)*512 + 256 + k)*256 + (n-2560)];
      else               v = cg_Ws[((l*2+1)*512 + 256 + k)*256 + (n-2816)];
      wt_opp[t] = f2b(v);
    }
    return;
  }
  idx -= 2 * 2359296;
  if (idx < 196608) {
    int l = idx / 65536, r = idx - l * 65536;
    int j = r & 7, lane = (r >> 3) & 63, blk = r >> 9;
    int kb = blk & 7, nb = blk >> 3;
    int n = nb * 16 + (lane & 15);
    int k = kb * 32 + (lane >> 4) * 8 + j;
    node_wt[idx] = f2b(node_W[(l*256 + k)*256 + n]);
    return;
  }
  idx -= 196608;
  if (idx < 8192) {
    int r = idx;
    int j = r & 7, lane = (r >> 3) & 63, blk = r >> 9;
    int nb = blk;
    int n = nb * 16 + (lane & 15);
    int k = (lane >> 4) * 8 + j;
    enc_wt[idx] = f2b(enc_W[k*256 + n]);
    return;
  }
  idx -= 8192;
  if (idx < 32768) {
    int r = idx;
    int j = r & 7, lane = (r >> 3) & 63, blk = r >> 9;
    int kb = blk & 7, nb = blk >> 3;
    int n = nb * 16 + (lane & 15);
    int k = kb * 32 + (lane >> 4) * 8 + j;
    fin_w1t[idx] = f2b(fin_W1[k*128 + n]);
    return;
  }
  idx -= 32768;
  if (idx < 9216) {
    int l = idx / 3072, n = idx - l * 3072;
    float v;
    if (n < 1024)      v = gat_bl[(l*2+0)*1024 + n];
    else if (n < 2048) v = gat_br[(l*2+1)*1024 + (n-1024)];
    else if (n < 2560) v = 0.f;
    else if (n < 2816) v = cg_bf[(l*2+1)*256 + (n-2560)];
    else               v = cg_bs[(l*2+1)*256 + (n-2816)];
    bias_my[idx] = v;
    return;
  }
  idx -= 9216;
  if (idx < 9216) {
    int l = idx / 3072, n = idx - l * 3072;
    float v;
    if (n < 1024)      v = gat_br[(l*2+0)*1024 + n];
    else if (n < 2048) v = gat_bl[(l*2+1)*1024 + (n-1024)];
    else if (n < 2304) v = cg_bf[(l*2+0)*256 + (n-2048)];
    else if (n < 2560) v = cg_bs[(l*2+0)*256 + (n-2304)];
    else               v = 0.f;
    bias_opp[idx] = v;
    return;
  }
  idx -= 9216;
  if (idx < 2 * 393216) {
    xb[idx] = f2b(idx < 393216 ? x_my[idx] : x_opp[idx - 393216]);
  }
}

// ---------------------------------------------------------------------------
// bf16 GEMM v7 (unchanged): used for enc/fin (small-N, row-major out).
// ---------------------------------------------------------------------------
__global__ __launch_bounds__(256) void gemm64(
    const unsigned short* __restrict__ A, const unsigned short* __restrict__ Ab,
    int lda,
    const unsigned short* __restrict__ Wp, const unsigned short* __restrict__ Wpb,
    const float* __restrict__ bias, const float* __restrict__ biasb,
    unsigned short* __restrict__ C, unsigned short* __restrict__ Cb,
    int ldc, int K, int act, int bx_split)
{
  __shared__ __align__(16) unsigned short lA[64 * 256];
  const int tid = threadIdx.x;
  const int lane = tid & 63;
  const int w = tid >> 6;
  const int wr = w >> 1, wc = w & 1;
  const int r0 = lane & 15, kq = lane >> 4;
  const int KT = K >> 5;
  const int gm = (K >> 3) - 1;
  const int rmask = gm > 7 ? 7 : gm;
  const int gsh = __popc((unsigned)gm);

  const unsigned short *Ap, *Wsel;
  const float* bp;
  unsigned short* Cp;
  int tileM;
  if ((int)blockIdx.x < bx_split) {
    Ap = A;  Wsel = Wp;  bp = bias;  Cp = C;  tileM = blockIdx.x * 64;
  } else {
    Ap = Ab; Wsel = Wpb; bp = biasb; Cp = Cb; tileM = (blockIdx.x - bx_split) * 64;
  }
  const int tileN = blockIdx.y * 128;

  for (int rd = 0; rd < KT; ++rd) {
    int idx = rd * 256 + tid;
    int row = idx >> gsh;
    int g = idx & gm;
    load_lds16(Ap + (size_t)(tileM + row) * lda + ((g ^ (row & rmask)) << 3),
               (char*)lA + idx * 16);
  }

  const int nblk0 = (tileN >> 4) + wc * 4;
  const unsigned short* wn0 = Wsel + ((size_t)(nblk0 + 0) * KT * 64 + lane) * 8;
  const unsigned short* wn1 = Wsel + ((size_t)(nblk0 + 1) * KT * 64 + lane) * 8;
  const unsigned short* wn2 = Wsel + ((size_t)(nblk0 + 2) * KT * 64 + lane) * 8;
  const unsigned short* wn3 = Wsel + ((size_t)(nblk0 + 3) * KT * 64 + lane) * 8;

  short8 b0_0 = *(const short8*)wn0;
  short8 b0_1 = *(const short8*)wn1;
  short8 b0_2 = *(const short8*)wn2;
  short8 b0_3 = *(const short8*)wn3;
  short8 b1_0 = b0_0, b1_1 = b0_1, b1_2 = b0_2, b1_3 = b0_3;
  if (KT > 1) {
    b1_0 = *(const short8*)(wn0 + 512);
    b1_1 = *(const short8*)(wn1 + 512);
    b1_2 = *(const short8*)(wn2 + 512);
    b1_3 = *(const short8*)(wn3 + 512);
  }

  f32x4 acc[2][4];
#pragma unroll
  for (int m = 0; m < 2; ++m)
#pragma unroll
    for (int n = 0; n < 4; ++n)
      acc[m][n] = (f32x4){0.f, 0.f, 0.f, 0.f};

  const int rb0 = (wr * 32 + r0) * K;
  const int rb1 = (wr * 32 + 16 + r0) * K;
  const int rx = r0 & rmask;

  __syncthreads();

  for (int kt = 0; kt < KT; ++kt) {
    short8 b2_0 = b1_0, b2_1 = b1_1, b2_2 = b1_2, b2_3 = b1_3;
    if (kt + 2 < KT) {
      const int o = (kt + 2) * 512;
      b2_0 = *(const short8*)(wn0 + o);
      b2_1 = *(const short8*)(wn1 + o);
      b2_2 = *(const short8*)(wn2 + o);
      b2_3 = *(const short8*)(wn3 + o);
    }
    const int p = (((kt << 2) + kq) ^ rx) * 8;
    short8 af0 = *(const short8*)&lA[rb0 + p];
    short8 af1 = *(const short8*)&lA[rb1 + p];
    acc[0][0] = __builtin_amdgcn_mfma_f32_16x16x32_bf16(b0_0, af0, acc[0][0], 0, 0, 0);
    acc[0][1] = __builtin_amdgcn_mfma_f32_16x16x32_bf16(b0_1, af0, acc[0][1], 0, 0, 0);
    acc[0][2] = __builtin_amdgcn_mfma_f32_16x16x32_bf16(b0_2, af0, acc[0][2], 0, 0, 0);
    acc[0][3] = __builtin_amdgcn_mfma_f32_16x16x32_bf16(b0_3, af0, acc[0][3], 0, 0, 0);
    acc[1][0] = __builtin_amdgcn_mfma_f32_16x16x32_bf16(b0_0, af1, acc[1][0], 0, 0, 0);
    acc[1][1] = __builtin_amdgcn_mfma_f32_16x16x32_bf16(b0_1, af1, acc[1][1], 0, 0, 0);
    acc[1][2] = __builtin_amdgcn_mfma_f32_16x16x32_bf16(b0_2, af1, acc[1][2], 0, 0, 0);
    acc[1][3] = __builtin_amdgcn_mfma_f32_16x16x32_bf16(b0_3, af1, acc[1][3], 0, 0, 0);
    b0_0 = b1_0; b0_1 = b1_1; b0_2 = b1_2; b0_3 = b1_3;
    b1_0 = b2_0; b1_1 = b2_1; b1_2 = b2_2; b1_3 = b2_3;
  }

  unsigned short* cT = lA;
  __syncthreads();
#pragma unroll
  for (int m = 0; m < 2; ++m) {
    const int rl = wr * 32 + m * 16 + r0;
#pragma unroll
    for (int n = 0; n < 4; ++n) {
      const int cl = wc * 64 + n * 16 + kq * 4;
      const f32x4 bv = *(const f32x4*)&bp[tileN + cl];
      float v0 = acc[m][n][0] + bv[0];
      float v1 = acc[m][n][1] + bv[1];
      float v2 = acc[m][n][2] + bv[2];
      float v3 = acc[m][n][3] + bv[3];
      if (act) {
        v0 = v0 > 0.f ? v0 : 128.f * v0;
        v1 = v1 > 0.f ? v1 : 128.f * v1;
        v2 = v2 > 0.f ? v2 : 128.f * v2;
        v3 = v3 > 0.f ? v3 : 128.f * v3;
      }
      uint2 pk;
      pk.x = (unsigned)f2b(v0) | ((unsigned)f2b(v1) << 16);
      pk.y = (unsigned)f2b(v2) | ((unsigned)f2b(v3) << 16);
      *(uint2*)&cT[rl * 132 + cl] = pk;
    }
  }
  __syncthreads();
#pragma unroll
  for (int it = 0; it < 4; ++it) {
    const int idx = it * 256 + tid;
    const int row = idx >> 4, ch = idx & 15;
    const uint4 val = *(const uint4*)&cT[row * 132 + ch * 8];
    *(uint4*)(Cp + (size_t)(tileM + row) * ldc + tileN + ch * 8) = val;
  }
}

// ---------------------------------------------------------------------------
// gemm64p v4: persistent-A, XCD-type-partitioned, DEPTH-4 B prefetch (4-slot
// register ring, fully unrolled kt loop -> static indices). LDS-only barriers.
// ---------------------------------------------------------------------------
__global__ __launch_bounds__(256) void gemm64p(
    const unsigned short* __restrict__ A, const unsigned short* __restrict__ Ab,
    const unsigned short* __restrict__ Wp, const unsigned short* __restrict__ Wpb,
    const float* __restrict__ bias, const float* __restrict__ biasb,
    unsigned short* __restrict__ C, unsigned short* __restrict__ Cb)
{
  const int K = 256, KT = 8;
  __shared__ __align__(16) unsigned short lA[64 * 256];
  __shared__ __align__(16) unsigned short cT[64 * 132];
  const int tid = threadIdx.x;
  const int lane = tid & 63;
  const int w = tid >> 6;
  const int wr = w >> 1, wc = w & 1;
  const int r0 = lane & 15, kq = lane >> 4;

  const int bx = (int)blockIdx.x;
  const int isopp = (bx & 4) >> 2;            // XCD 0-3 -> my, 4-7 -> opp
  const int idxm = (bx >> 3) * 4 + (bx & 3);  // 0..191 within type

  const unsigned short *Ap, *Wsel;
  const float* bp;
  unsigned short* Cp;
  if (!isopp) { Ap = A;  Wsel = Wp;  bp = bias;  Cp = C;  }
  else        { Ap = Ab; Wsel = Wpb; bp = biasb; Cp = Cb; }
  const int tileM = idxm * 64;

  for (int rd = 0; rd < KT; ++rd) {
    int idx = rd * 256 + tid;
    int row = idx >> 5;
    int g = idx & 31;
    load_lds16(Ap + (size_t)(tileM + row) * K + ((g ^ (row & 7)) << 3),
               (char*)lA + idx * 16);
  }

  const int rb0 = (wr * 32 + r0) * K;
  const int rb1 = (wr * 32 + 16 + r0) * K;
  const int rx = r0 & 7;

  __syncthreads();   // A tile resident (global_load_lds needs full drain)

  for (int nn = 0; nn < 12; ++nn) {
    const int cb = (int)blockIdx.y * 12 + nn;
    const int tileN = cb * 128;
    const int nblk0 = (tileN >> 4) + wc * 4;
    const unsigned short* wn0 = Wsel + ((size_t)(nblk0 + 0) * KT * 64 + lane) * 8;
    const unsigned short* wn1 = Wsel + ((size_t)(nblk0 + 1) * KT * 64 + lane) * 8;
    const unsigned short* wn2 = Wsel + ((size_t)(nblk0 + 2) * KT * 64 + lane) * 8;
    const unsigned short* wn3 = Wsel + ((size_t)(nblk0 + 3) * KT * 64 + lane) * 8;

    // depth-4 register ring: bq[slot][frag], fully static indices
    short8 bq[4][4];
#pragma unroll
    for (int sl = 0; sl < 4; ++sl) {
      const int o = sl * 512;
      bq[sl][0] = *(const short8*)(wn0 + o);
      bq[sl][1] = *(const short8*)(wn1 + o);
      bq[sl][2] = *(const short8*)(wn2 + o);
      bq[sl][3] = *(const short8*)(wn3 + o);
    }

    f32x4 acc[2][4];
#pragma unroll
    for (int m = 0; m < 2; ++m)
#pragma unroll
      for (int n = 0; n < 4; ++n)
        acc[m][n] = (f32x4){0.f, 0.f, 0.f, 0.f};

#pragma unroll
    for (int kt = 0; kt < KT; ++kt) {
      const int sl = kt & 3;
      short8 c0 = bq[sl][0], c1 = bq[sl][1], c2 = bq[sl][2], c3 = bq[sl][3];
      if (kt + 4 < KT) {
        const int o = (kt + 4) * 512;
        bq[sl][0] = *(const short8*)(wn0 + o);
        bq[sl][1] = *(const short8*)(wn1 + o);
        bq[sl][2] = *(const short8*)(wn2 + o);
        bq[sl][3] = *(const short8*)(wn3 + o);
      }
      const int p = (((kt << 2) + kq) ^ rx) * 8;
      short8 af0 = *(const short8*)&lA[rb0 + p];
      short8 af1 = *(const short8*)&lA[rb1 + p];
      acc[0][0] = __builtin_amdgcn_mfma_f32_16x16x32_bf16(c0, af0, acc[0][0], 0, 0, 0);
      acc[0][1] = __builtin_amdgcn_mfma_f32_16x16x32_bf16(c1, af0, acc[0][1], 0, 0, 0);
      acc[0][2] = __builtin_amdgcn_mfma_f32_16x16x32_bf16(c2, af0, acc[0][2], 0, 0, 0);
      acc[0][3] = __builtin_amdgcn_mfma_f32_16x16x32_bf16(c3, af0, acc[0][3], 0, 0, 0);
      acc[1][0] = __builtin_amdgcn_mfma_f32_16x16x32_bf16(c0, af1, acc[1][0], 0, 0, 0);
      acc[1][1] = __builtin_amdgcn_mfma_f32_16x16x32_bf16(c1, af1, acc[1][1], 0, 0, 0);
      acc[1][2] = __builtin_amdgcn_mfma_f32_16x16x32_bf16(c2, af1, acc[1][2], 0, 0, 0);
      acc[1][3] = __builtin_amdgcn_mfma_f32_16x16x32_bf16(c3, af1, acc[1][3], 0, 0, 0);
    }

    lds_barrier();   // prior nn's cT reads complete (LDS-only)
#pragma unroll
    for (int m = 0; m < 2; ++m) {
      const int rl = wr * 32 + m * 16 + r0;
#pragma unroll
      for (int n = 0; n < 4; ++n) {
        const int cl = wc * 64 + n * 16 + kq * 4;
        const f32x4 bv = *(const f32x4*)&bp[tileN + cl];
        uint2 pk;
        pk.x = (unsigned)f2b(acc[m][n][0] + bv[0]) |
               ((unsigned)f2b(acc[m][n][1] + bv[1]) << 16);
        pk.y = (unsigned)f2b(acc[m][n][2] + bv[2]) |
               ((unsigned)f2b(acc[m][n][3] + bv[3]) << 16);
        *(uint2*)&cT[rl * 132 + cl] = pk;
      }
    }
    lds_barrier();   // cT writes visible (LDS-only)
    unsigned short* dstb = Cp + ((size_t)cb * NNODES + tileM) * 128;
#pragma unroll
    for (int it = 0; it < 4; ++it) {
      const int idx = it * 256 + tid;
      const uint4 val = *(const uint4*)&cT[(idx >> 4) * 132 + (idx & 15) * 8];
      *(uint4*)(dstb + (size_t)idx * 8) = val;
    }
  }
}

// ---------------------------------------------------------------------------
// GATv2 edge stage v10 (unchanged): group-per-(d,h), shuffle softmax.
// ---------------------------------------------------------------------------
#define SX 260
__global__ __launch_bounds__(256) void gat_edge(
    const unsigned short* __restrict__ proj_my,
    const unsigned short* __restrict__ proj_op,
    const int* __restrict__ e_beats, const int* __restrict__ e_rl,
    const float* __restrict__ attL, const float* __restrict__ gbiasL,
    unsigned short* __restrict__ gat_op, unsigned short* __restrict__ gat_my)
{
  __shared__ __align__(16) unsigned short xl[48 * SX];
  __shared__ __align__(16) float attS[4 * SX];
  __shared__ __align__(16) float A2f[12 * 48];
  __shared__ int multI[144];
  __shared__ unsigned char srcG[12][12];
  __shared__ unsigned char multG[12][12];
  __shared__ int cntG[12];
  const int bid = blockIdx.x, tid = threadIdx.x;
  const int dir = bid >= NGR;
  const int g = dir ? bid - NGR : bid;
  const int base = g * 12;

  const unsigned short *Psrc, *Pdst;
  int pcol0;
  const int* edges;
  const float* att;
  const float* gbias;
  unsigned short* outp;
  if (!dir) {
    Psrc = proj_my; Pdst = proj_op; pcol0 = 0;
    edges = e_beats; att = attL; gbias = gbiasL; outp = gat_op;
  } else {
    Psrc = proj_op; Pdst = proj_my; pcol0 = 1024;
    edges = e_rl; att = attL + 1024; gbias = gbiasL + 256; outp = gat_my;
  }

  if (tid < 144) multI[tid] = 0;
  for (int i = tid; i < 576; i += 256) A2f[i] = 0.f;
  __syncthreads();
  if (tid < 72) {
    const int s = edges[g * 72 + tid] - base;
    const int d = edges[ETOT + g * 72 + tid] - base;
    atomicAdd(&multI[d * 12 + s], 1);
  }
  for (int i = tid; i < 1024; i += 256)
    attS[(i >> 8) * SX + (i & 255)] = att[i];
  for (int i = tid; i < 3072; i += 256) {
    int s = i >> 8, c4 = (i & 255) * 4;
    int h = c4 >> 8, cc = c4 & 255;
    *(ushort4*)&xl[(h * 12 + s) * SX + cc] =
        *(const ushort4*)pnode(Psrc, pcol0 + c4, base + s);
  }
  __syncthreads();

  if (tid < 12) {
    int n = 0;
    for (int s = 0; s < 12; ++s) {
      const int m = multI[tid * 12 + s];
      if (m > 0) { srcG[tid][n] = (unsigned char)s; multG[tid][n] = (unsigned char)m; ++n; }
    }
    cntG[tid] = n;
  }
  __syncthreads();

  for (int r = 0; r < 3; ++r) {
    const int slot = r * 256 + tid;
    const int g16 = slot >> 4, lane16 = slot & 15;
    const int d = g16 >> 2, h = g16 & 3;
    const int cnt = cntG[d];
    const int ch0 = lane16 * 16;
    const unsigned short* prp = pnode(Pdst, pcol0 + h * 256 + ch0, base + d);
    const ushort4 xr0 = *(const ushort4*)(prp);
    const ushort4 xr1 = *(const ushort4*)(prp + 4);
    const ushort4 xr2 = *(const ushort4*)(prp + 8);
    const ushort4 xr3 = *(const ushort4*)(prp + 12);
    const float* pa = &attS[h * SX + ch0];
    const f32x4 at0 = *(const f32x4*)(pa);
    const f32x4 at1 = *(const f32x4*)(pa + 4);
    const f32x4 at2 = *(const f32x4*)(pa + 8);
    const f32x4 at3 = *(const f32x4*)(pa + 12);

    float myalpha = -1e30f;
    for (int j = 0; j < cnt; ++j) {
      const int s = srcG[d][j];
      const unsigned short* pl = &xl[(h * 12 + s) * SX + ch0];
      float p = 0.f;
      {
        ushort4 a4 = *(const ushort4*)(pl);
        float v0 = b2f(a4.x) + b2f(xr0.x); v0 = fmaxf(v0, 0.2f * v0);
        float v1 = b2f(a4.y) + b2f(xr0.y); v1 = fmaxf(v1, 0.2f * v1);
        float v2 = b2f(a4.z) + b2f(xr0.z); v2 = fmaxf(v2, 0.2f * v2);
        float v3 = b2f(a4.w) + b2f(xr0.w); v3 = fmaxf(v3, 0.2f * v3);
        p = fmaf(v0, at0[0], p); p = fmaf(v1, at0[1], p);
        p = fmaf(v2, at0[2], p); p = fmaf(v3, at0[3], p);
      }
      {
        ushort4 a4 = *(const ushort4*)(pl + 4);
        float v0 = b2f(a4.x) + b2f(xr1.x); v0 = fmaxf(v0, 0.2f * v0);
        float v1 = b2f(a4.y) + b2f(xr1.y); v1 = fmaxf(v1, 0.2f * v1);
        float v2 = b2f(a4.z) + b2f(xr1.z); v2 = fmaxf(v2, 0.2f * v2);
        float v3 = b2f(a4.w) + b2f(xr1.w); v3 = fmaxf(v3, 0.2f * v3);
        p = fmaf(v0, at1[0], p); p = fmaf(v1, at1[1], p);
        p = fmaf(v2, at1[2], p); p = fmaf(v3, at1[3], p);
      }
      {
        ushort4 a4 = *(const ushort4*)(pl + 8);
        float v0 = b2f(a4.x) + b2f(xr2.x); v0 = fmaxf(v0, 0.2f * v0);
        float v1 = b2f(a4.y) + b2f(xr2.y); v1 = fmaxf(v1, 0.2f * v1);
        float v2 = b2f(a4.z) + b2f(xr2.z); v2 = fmaxf(v2, 0.2f * v2);
        float v3 = b2f(a4.w) + b2f(xr2.w); v3 = fmaxf(v3, 0.2f * v3);
        p = fmaf(v0, at2[0], p); p = fmaf(v1, at2[1], p);
        p = fmaf(v2, at2[2], p); p = fmaf(v3, at2[3], p);
      }
      {
        ushort4 a4 = *(const ushort4*)(pl + 12);
        float v0 = b2f(a4.x) + b2f(xr3.x); v0 = fmaxf(v0, 0.2f * v0);
        float v1 = b2f(a4.y) + b2f(xr3.y); v1 = fmaxf(v1, 0.2f * v1);
        float v2 = b2f(a4.z) + b2f(xr3.z); v2 = fmaxf(v2, 0.2f * v2);
        float v3 = b2f(a4.w) + b2f(xr3.w); v3 = fmaxf(v3, 0.2f * v3);
        p = fmaf(v0, at3[0], p); p = fmaf(v1, at3[1], p);
        p = fmaf(v2, at3[2], p); p = fmaf(v3, at3[3], p);
      }
#pragma unroll
      for (int off = 1; off < 16; off <<= 1) p += __shfl_xor(p, off, 64);
      if (j == lane16) myalpha = p * LOG2E;
    }
    float m = myalpha;
#pragma unroll
    for (int off = 1; off < 16; off <<= 1) m = fmaxf(m, __shfl_xor(m, off, 64));
    const float wv = __builtin_amdgcn_exp2f(myalpha - m);
    const float mw = (lane16 < cnt) ? (float)multG[d][lane16] * wv : 0.f;
    float den = mw;
#pragma unroll
    for (int off = 1; off < 16; off <<= 1) den += __shfl_xor(den, off, 64);
    const float inv = 0.25f * __builtin_amdgcn_rcpf(den + 1e-16f);
    if (lane16 < cnt) A2f[d * 48 + h * 12 + srcG[d][lane16]] = mw * inv;
  }
  __syncthreads();

  {
    const int c = tid;
    float xlv[48];
#pragma unroll
    for (int j = 0; j < 48; ++j) xlv[j] = b2f(xl[j * SX + c]);
    const float gb = gbias[c];
#pragma unroll
    for (int d = 0; d < 12; ++d) {
      const f32x4* arow = (const f32x4*)&A2f[d * 48];
      float s = 0.f;
#pragma unroll
      for (int jj = 0; jj < 12; ++jj) {
        f32x4 a4 = arow[jj];
        s = fmaf(a4.x, xlv[jj * 4 + 0], s);
        s = fmaf(a4.y, xlv[jj * 4 + 1], s);
        s = fmaf(a4.z, xlv[jj * 4 + 2], s);
        s = fmaf(a4.w, xlv[jj * 4 + 3], s);
      }
      outp[(size_t)(base + d) * 256 + c] = f2b(s + gb);
    }
  }
}

// ---------------------------------------------------------------------------
// cg_fused v2 (unchanged): dedup'd CGConv combine + node MFMA.
// ---------------------------------------------------------------------------
__global__ __launch_bounds__(256) void cg_fused(
    const unsigned short* __restrict__ proj_my,
    const unsigned short* __restrict__ proj_op,
    unsigned short* __restrict__ Hmy, unsigned short* __restrict__ Hopp,
    const unsigned short* __restrict__ gat_my, const unsigned short* __restrict__ gat_op,
    const int* __restrict__ e_loses, const int* __restrict__ e_rb,
    const unsigned short* __restrict__ node_wtL, const float* __restrict__ node_bL)
{
  __shared__ __align__(8) unsigned short df[3072], dsb[3072];
  __shared__ __align__(8) unsigned short sfb[3072], ssb[3072];
  __shared__ __align__(16) unsigned short At[16 * 264];
  __shared__ int multI[144];
  __shared__ unsigned char srcG[12][12];
  __shared__ unsigned char multG[12][12];
  __shared__ int cntG[12];
  const int bid = blockIdx.x, tid = threadIdx.x;
  const int dir = bid >= NGR;
  const int g = dir ? bid - NGR : bid;
  const int base = g * 12;

  const unsigned short *Pd, *Ps, *gatp;
  unsigned short *Hout;
  int fcol, scol;
  const int* edges;
  if (!dir) {
    Pd = proj_op; Ps = proj_my; fcol = 2048; scol = 2304;
    Hout = Hopp; gatp = gat_op; edges = e_loses;
  } else {
    Pd = proj_my; Ps = proj_op; fcol = 2560; scol = 2816;
    Hout = Hmy; gatp = gat_my; edges = e_rb;
  }

  if (tid < 144) multI[tid] = 0;
  __syncthreads();
  if (tid < 72) {
    const int s = edges[g * 72 + tid] - base;
    const int d = edges[ETOT + g * 72 + tid] - base;
    atomicAdd(&multI[d * 12 + s], 1);
  }
  for (int i = tid; i < 768; i += 256) {
    int s = i >> 6, c4 = (i & 63) * 4;
    const int node = base + s;
    *(ushort4*)&df[s * 256 + c4]  = *(const ushort4*)pnode(Pd, fcol + c4, node);
    *(ushort4*)&dsb[s * 256 + c4] = *(const ushort4*)pnode(Pd, scol + c4, node);
    *(ushort4*)&sfb[s * 256 + c4] = *(const ushort4*)pnode(Ps, fcol + c4, node);
    *(ushort4*)&ssb[s * 256 + c4] = *(const ushort4*)pnode(Ps, scol + c4, node);
  }
  const int c = tid;
  float hv[12], gv[12];
#pragma unroll
  for (int d = 0; d < 12; ++d) {
    const size_t o = (size_t)(base + d) * 256 + c;
    hv[d] = b2f(Hout[o]);
    gv[d] = b2f(gatp[o]);
  }
  __syncthreads();
  if (tid < 12) {
    int n = 0;
    for (int s = 0; s < 12; ++s) {
      const int m = multI[tid * 12 + s];
      if (m > 0) { srcG[tid][n] = (unsigned char)s; multG[tid][n] = (unsigned char)m; ++n; }
    }
    cntG[tid] = n;
  }
  __syncthreads();
  for (int d = 0; d < 12; ++d) {
    const float fd = b2f(df[d * 256 + c]);
    const float sd = b2f(dsb[d * 256 + c]);
    const int n = cntG[d];
    float acc = 0.f;
    for (int j = 0; j < n; ++j) {
      const int s = srcG[d][j];
      const float mlt = (float)multG[d][j];
      const float zf = fd + b2f(sfb[s * 256 + c]);
      const float zs = sd + b2f(ssb[s * 256 + c]);
      const float gate = __builtin_amdgcn_rcpf(1.f + __builtin_amdgcn_exp2f(-LOG2E * zf));
      const float e2 = __builtin_amdgcn_exp2f(-LOG2E * fabsf(zs));
      const float sp = fmaxf(zs, 0.f) + LN2 * __builtin_amdgcn_logf(1.f + e2);
      acc = fmaf(mlt * gate, sp, acc);
    }
    At[d * 264 + c] = f2b(hv[d] + gv[d] + acc);
  }
  __syncthreads();
  {
    const int w = tid >> 6, lane = tid & 63;
    const int r0 = lane & 15, kq = lane >> 4;
#pragma unroll
    for (int n = 0; n < 4; ++n) {
      const unsigned short* wb = node_wtL + ((size_t)(w * 4 + n) * 8) * 512 + lane * 8;
      f32x4 a = (f32x4){0.f, 0.f, 0.f, 0.f};
#pragma unroll
      for (int kt = 0; kt < 8; ++kt) {
        short8 wf = *(const short8*)(wb + kt * 512);
        short8 af = *(const short8*)&At[r0 * 264 + kt * 32 + kq * 8];
        a = __builtin_amdgcn_mfma_f32_16x16x32_bf16(wf, af, a, 0, 0, 0);
      }
      if (r0 < 12) {
        const int col0 = w * 64 + n * 16 + kq * 4;
        const f32x4 bv = *(const f32x4*)&node_bL[col0];
        uint2 pk;
        pk.x = (unsigned)f2b(a[0] + bv[0]) | ((unsigned)f2b(a[1] + bv[1]) << 16);
        pk.y = (unsigned)f2b(a[2] + bv[2]) | ((unsigned)f2b(a[3] + bv[3]) << 16);
        *(uint2*)(Hout + (size_t)(base + r0) * 256 + col0) = pk;
      }
    }
  }
}

// ---------------------------------------------------------------------------
// logits: one wave per node, dot(f[128], W2) + b2
// ---------------------------------------------------------------------------
__global__ __launch_bounds__(256) void logits_kernel(
    const unsigned short* __restrict__ f, const float* __restrict__ W2,
    const float* __restrict__ b2, float* __restrict__ out)
{
  const int node = blockIdx.x * 4 + (threadIdx.x >> 6);
  const int lane = threadIdx.x & 63;
  const size_t o = (size_t)node * 128 + lane * 2;
  float s = b2f(f[o]) * W2[lane * 2] + b2f(f[o + 1]) * W2[lane * 2 + 1];
  for (int d = 32; d > 0; d >>= 1) s += __shfl_down(s, d, 64);
  if (lane == 0) out[node] = s + b2[0];
}

// ---------------------------------------------------------------------------
extern "C" void kernel_launch(void* const* d_in, const int* in_sizes, int n_in,
                              void* d_out, int out_size, void* d_ws, size_t ws_size,
                              hipStream_t stream) {
  const float* x_my    = (const float*)d_in[0];
  const float* x_opp   = (const float*)d_in[1];
  const int*   e_beats = (const int*)d_in[2];
  const int*   e_loses = (const int*)d_in[3];
  const int*   e_rb    = (const int*)d_in[4];
  const int*   e_rl    = (const int*)d_in[5];
  const float* enc_W   = (const float*)d_in[7];
  const float* enc_b   = (const float*)d_in[8];
  const float* gat_Wl  = (const float*)d_in[9];
  const float* gat_bl  = (const float*)d_in[10];
  const float* gat_Wr  = (const float*)d_in[11];
  const float* gat_br  = (const float*)d_in[12];
  const float* gat_att = (const float*)d_in[13];
  const float* gat_bsp = (const float*)d_in[14];
  const float* cg_Wf   = (const float*)d_in[15];
  const float* cg_bf   = (const float*)d_in[16];
  const float* cg_Ws   = (const float*)d_in[17];
  const float* cg_bs   = (const float*)d_in[18];
  const float* node_W  = (const float*)d_in[19];
  const float* node_b  = (const float*)d_in[20];
  const float* fin_W1  = (const float*)d_in[21];
  const float* fin_b1  = (const float*)d_in[22];
  const float* fin_W2  = (const float*)d_in[23];
  const float* fin_b2  = (const float*)d_in[24];

  char* wsp = (char*)d_ws;
  size_t off = 0;
  auto alloc = [&](size_t b) { char* p = wsp + off; off += (b + 255) & ~(size_t)255; return p; };
  unsigned short* wt_my   = (unsigned short*)alloc((size_t)2359296 * 2);
  unsigned short* wt_opp  = (unsigned short*)alloc((size_t)2359296 * 2);
  unsigned short* node_wt = (unsigned short*)alloc((size_t)196608 * 2);
  unsigned short* enc_wt  = (unsigned short*)alloc((size_t)8192 * 2);
  unsigned short* fin_w1t = (unsigned short*)alloc((size_t)32768 * 2);
  float*          bias_my = (float*)alloc((size_t)9216 * 4);
  float*          bias_op = (float*)alloc((size_t)9216 * 4);
  unsigned short* xb      = (unsigned short*)alloc((size_t)786432 * 2);
  unsigned short* Hb      = (unsigned short*)alloc((size_t)2 * NNODES * 256 * 2);
  unsigned short* proj_my = (unsigned short*)alloc((size_t)NNODES * 3072 * 2);
  unsigned short* proj_op = (unsigned short*)alloc((size_t)NNODES * 3072 * 2);
  unsigned short* gat_my  = (unsigned short*)alloc((size_t)NNODES * 256 * 2);
  unsigned short* gat_op  = (unsigned short*)alloc((size_t)NNODES * 256 * 2);
  unsigned short* fbuf    = (unsigned short*)alloc((size_t)NNODES * 128 * 2);

  const int PACK_TOTAL = 2 * 2359296 + 196608 + 8192 + 32768 + 2 * 9216 + 2 * 393216;
  pack_kernel<<<(PACK_TOTAL + 255) / 256, 256, 0, stream>>>(
      gat_Wl, gat_Wr, cg_Wf, cg_Ws, node_W, enc_W, fin_W1,
      gat_bl, gat_br, cg_bf, cg_bs, x_my, x_opp,
      wt_my, wt_opp, node_wt, enc_wt, fin_w1t, bias_my, bias_op, xb);

  unsigned short* Hmy  = Hb;
  unsigned short* Hopp = Hb + (size_t)NNODES * 256;

  // encoder: h = x @ enc_W + enc_b  (M = 24576, N = 256, K = 32)
  gemm64<<<dim3(384, 2), 256, 0, stream>>>(
      xb, xb, 32, enc_wt, enc_wt, enc_b, enc_b, Hb, Hb, 256, 32, 0, 384);

  for (int l = 0; l < 3; ++l) {
    gemm64p<<<dim3(384, 2), 256, 0, stream>>>(
        Hmy, Hopp,
        wt_my + (size_t)l * 786432, wt_opp + (size_t)l * 786432,
        bias_my + l * 3072, bias_op + l * 3072,
        proj_my, proj_op);
    gat_edge<<<2 * NGR, 256, 0, stream>>>(
        proj_my, proj_op, e_beats, e_rl,
        gat_att + l * 2048, gat_bsp + l * 512, gat_op, gat_my);
    cg_fused<<<2 * NGR, 256, 0, stream>>>(
        proj_my, proj_op, Hmy, Hopp, gat_my, gat_op,
        e_loses, e_rb,
        node_wt + (size_t)l * 65536, node_b + l * 256);
  }

  gemm64<<<dim3(192, 1), 256, 0, stream>>>(
      Hmy, Hmy, 256, fin_w1t, fin_w1t, fin_b1, fin_b1, fbuf, fbuf, 128, 256, 1, 192);
  logits_kernel<<<NNODES / 4, 256, 0, stream>>>(fbuf, fin_W2, fin_b2, (float*)d_out);
}

// Round 23
// 447.832 us; speedup vs baseline: 1.0295x; 1.0203x over previous
//
#include <hip/hip_runtime.h>

#define NNODES 12288
#define ETOT   73728
#define NGR    1024
#define LOG2E  1.442695041f
#define LN2    0.6931471806f

typedef __attribute__((ext_vector_type(8))) short short8;
typedef __attribute__((ext_vector_type(4))) float f32x4;

__device__ __forceinline__ unsigned short f2b(float f) {
  return __builtin_bit_cast(unsigned short, (__bf16)f);
}
__device__ __forceinline__ float b2f(unsigned short u) {
  return __uint_as_float(((unsigned)u) << 16);
}
__device__ __forceinline__ void load_lds16(const void* g, void* l) {
  __builtin_amdgcn_global_load_lds(
      (const __attribute__((address_space(1))) unsigned int*)g,
      (__attribute__((address_space(3))) unsigned int*)l, 16, 0, 0);
}
// LDS-only barrier: waits LDS ops, leaves global stores/loads in flight.
__device__ __forceinline__ void lds_barrier() {
  asm volatile("s_waitcnt lgkmcnt(0)" ::: "memory");
  __builtin_amdgcn_s_barrier();
}

// proj layout: [colblk = col>>7][node][col&127]
__device__ __forceinline__ const unsigned short* pnode(
    const unsigned short* P, int col0, int node) {
  return P + ((size_t)(col0 >> 7) * NNODES + node) * 128 + (col0 & 127);
}

// ---------------------------------------------------------------------------
// Pack (unchanged): weights in MFMA-fragment order
// ---------------------------------------------------------------------------
__global__ void pack_kernel(
    const float* __restrict__ gat_Wl, const float* __restrict__ gat_Wr,
    const float* __restrict__ cg_Wf, const float* __restrict__ cg_Ws,
    const float* __restrict__ node_W, const float* __restrict__ enc_W,
    const float* __restrict__ fin_W1,
    const float* __restrict__ gat_bl, const float* __restrict__ gat_br,
    const float* __restrict__ cg_bf, const float* __restrict__ cg_bs,
    const float* __restrict__ x_my, const float* __restrict__ x_opp,
    unsigned short* __restrict__ wt_my, unsigned short* __restrict__ wt_opp,
    unsigned short* __restrict__ node_wt, unsigned short* __restrict__ enc_wt,
    unsigned short* __restrict__ fin_w1t,
    float* __restrict__ bias_my, float* __restrict__ bias_opp,
    unsigned short* __restrict__ xb)
{
  int idx = blockIdx.x * 256 + threadIdx.x;
  if (idx < 2 * 2359296) {
    int which = idx >= 2359296;
    int t = which ? idx - 2359296 : idx;
    int l = t / 786432;
    int r = t - l * 786432;
    int j = r & 7, lane = (r >> 3) & 63, blk = r >> 9;
    int kb = blk & 7, nb = blk >> 3;
    int n = nb * 16 + (lane & 15);
    int k = kb * 32 + (lane >> 4) * 8 + j;
    float v;
    if (!which) {
      if (n < 1024)      v = gat_Wl[((l*2+0)*256 + k)*1024 + n];
      else if (n < 2048) v = gat_Wr[((l*2+1)*256 + k)*1024 + (n-1024)];
      else if (n < 2304) v = cg_Wf[((l*2+0)*512 + 256 + k)*256 + (n-2048)];
      else if (n < 2560) v = cg_Ws[((l*2+0)*512 + 256 + k)*256 + (n-2304)];
      else if (n < 2816) v = cg_Wf[((l*2+1)*512 + k)*256 + (n-2560)];
      else               v = cg_Ws[((l*2+1)*512 + k)*256 + (n-2816)];
      wt_my[t] = f2b(v);
    } else {
      if (n < 1024)      v = gat_Wr[((l*2+0)*256 + k)*1024 + n];
      else if (n < 2048) v = gat_Wl[((l*2+1)*256 + k)*1024 + (n-1024)];
      else if (n < 2304) v = cg_Wf[((l*2+0)*512 + k)*256 + (n-2048)];
      else if (n < 2560) v = cg_Ws[((l*2+0)*512 + k)*256 + (n-2304)];
      else if (n < 2816) v = cg_Wf[((l*2+1)*512 + 256 + k)*256 + (n-2560)];
      else               v = cg_Ws[((l*2+1)*512 + 256 + k)*256 + (n-2816)];
      wt_opp[t] = f2b(v);
    }
    return;
  }
  idx -= 2 * 2359296;
  if (idx < 196608) {
    int l = idx / 65536, r = idx - l * 65536;
    int j = r & 7, lane = (r >> 3) & 63, blk = r >> 9;
    int kb = blk & 7, nb = blk >> 3;
    int n = nb * 16 + (lane & 15);
    int k = kb * 32 + (lane >> 4) * 8 + j;
    node_wt[idx] = f2b(node_W[(l*256 + k)*256 + n]);
    return;
  }
  idx -= 196608;
  if (idx < 8192) {
    int r = idx;
    int j = r & 7, lane = (r >> 3) & 63, blk = r >> 9;
    int nb = blk;
    int n = nb * 16 + (lane & 15);
    int k = (lane >> 4) * 8 + j;
    enc_wt[idx] = f2b(enc_W[k*256 + n]);
    return;
  }
  idx -= 8192;
  if (idx < 32768) {
    int r = idx;
    int j = r & 7, lane = (r >> 3) & 63, blk = r >> 9;
    int kb = blk & 7, nb = blk >> 3;
    int n = nb * 16 + (lane & 15);
    int k = kb * 32 + (lane >> 4) * 8 + j;
    fin_w1t[idx] = f2b(fin_W1[k*128 + n]);
    return;
  }
  idx -= 32768;
  if (idx < 9216) {
    int l = idx / 3072, n = idx - l * 3072;
    float v;
    if (n < 1024)      v = gat_bl[(l*2+0)*1024 + n];
    else if (n < 2048) v = gat_br[(l*2+1)*1024 + (n-1024)];
    else if (n < 2560) v = 0.f;
    else if (n < 2816) v = cg_bf[(l*2+1)*256 + (n-2560)];
    else               v = cg_bs[(l*2+1)*256 + (n-2816)];
    bias_my[idx] = v;
    return;
  }
  idx -= 9216;
  if (idx < 9216) {
    int l = idx / 3072, n = idx - l * 3072;
    float v;
    if (n < 1024)      v = gat_br[(l*2+0)*1024 + n];
    else if (n < 2048) v = gat_bl[(l*2+1)*1024 + (n-1024)];
    else if (n < 2304) v = cg_bf[(l*2+0)*256 + (n-2048)];
    else if (n < 2560) v = cg_bs[(l*2+0)*256 + (n-2304)];
    else               v = 0.f;
    bias_opp[idx] = v;
    return;
  }
  idx -= 9216;
  if (idx < 2 * 393216) {
    xb[idx] = f2b(idx < 393216 ? x_my[idx] : x_opp[idx - 393216]);
  }
}

// ---------------------------------------------------------------------------
// bf16 GEMM v7 (unchanged): used for enc/fin (small-N, row-major out).
// ---------------------------------------------------------------------------
__global__ __launch_bounds__(256) void gemm64(
    const unsigned short* __restrict__ A, const unsigned short* __restrict__ Ab,
    int lda,
    const unsigned short* __restrict__ Wp, const unsigned short* __restrict__ Wpb,
    const float* __restrict__ bias, const float* __restrict__ biasb,
    unsigned short* __restrict__ C, unsigned short* __restrict__ Cb,
    int ldc, int K, int act, int bx_split)
{
  __shared__ __align__(16) unsigned short lA[64 * 256];
  const int tid = threadIdx.x;
  const int lane = tid & 63;
  const int w = tid >> 6;
  const int wr = w >> 1, wc = w & 1;
  const int r0 = lane & 15, kq = lane >> 4;
  const int KT = K >> 5;
  const int gm = (K >> 3) - 1;
  const int rmask = gm > 7 ? 7 : gm;
  const int gsh = __popc((unsigned)gm);

  const unsigned short *Ap, *Wsel;
  const float* bp;
  unsigned short* Cp;
  int tileM;
  if ((int)blockIdx.x < bx_split) {
    Ap = A;  Wsel = Wp;  bp = bias;  Cp = C;  tileM = blockIdx.x * 64;
  } else {
    Ap = Ab; Wsel = Wpb; bp = biasb; Cp = Cb; tileM = (blockIdx.x - bx_split) * 64;
  }
  const int tileN = blockIdx.y * 128;

  for (int rd = 0; rd < KT; ++rd) {
    int idx = rd * 256 + tid;
    int row = idx >> gsh;
    int g = idx & gm;
    load_lds16(Ap + (size_t)(tileM + row) * lda + ((g ^ (row & rmask)) << 3),
               (char*)lA + idx * 16);
  }

  const int nblk0 = (tileN >> 4) + wc * 4;
  const unsigned short* wn0 = Wsel + ((size_t)(nblk0 + 0) * KT * 64 + lane) * 8;
  const unsigned short* wn1 = Wsel + ((size_t)(nblk0 + 1) * KT * 64 + lane) * 8;
  const unsigned short* wn2 = Wsel + ((size_t)(nblk0 + 2) * KT * 64 + lane) * 8;
  const unsigned short* wn3 = Wsel + ((size_t)(nblk0 + 3) * KT * 64 + lane) * 8;

  short8 b0_0 = *(const short8*)wn0;
  short8 b0_1 = *(const short8*)wn1;
  short8 b0_2 = *(const short8*)wn2;
  short8 b0_3 = *(const short8*)wn3;
  short8 b1_0 = b0_0, b1_1 = b0_1, b1_2 = b0_2, b1_3 = b0_3;
  if (KT > 1) {
    b1_0 = *(const short8*)(wn0 + 512);
    b1_1 = *(const short8*)(wn1 + 512);
    b1_2 = *(const short8*)(wn2 + 512);
    b1_3 = *(const short8*)(wn3 + 512);
  }

  f32x4 acc[2][4];
#pragma unroll
  for (int m = 0; m < 2; ++m)
#pragma unroll
    for (int n = 0; n < 4; ++n)
      acc[m][n] = (f32x4){0.f, 0.f, 0.f, 0.f};

  const int rb0 = (wr * 32 + r0) * K;
  const int rb1 = (wr * 32 + 16 + r0) * K;
  const int rx = r0 & rmask;

  __syncthreads();

  for (int kt = 0; kt < KT; ++kt) {
    short8 b2_0 = b1_0, b2_1 = b1_1, b2_2 = b1_2, b2_3 = b1_3;
    if (kt + 2 < KT) {
      const int o = (kt + 2) * 512;
      b2_0 = *(const short8*)(wn0 + o);
      b2_1 = *(const short8*)(wn1 + o);
      b2_2 = *(const short8*)(wn2 + o);
      b2_3 = *(const short8*)(wn3 + o);
    }
    const int p = (((kt << 2) + kq) ^ rx) * 8;
    short8 af0 = *(const short8*)&lA[rb0 + p];
    short8 af1 = *(const short8*)&lA[rb1 + p];
    acc[0][0] = __builtin_amdgcn_mfma_f32_16x16x32_bf16(b0_0, af0, acc[0][0], 0, 0, 0);
    acc[0][1] = __builtin_amdgcn_mfma_f32_16x16x32_bf16(b0_1, af0, acc[0][1], 0, 0, 0);
    acc[0][2] = __builtin_amdgcn_mfma_f32_16x16x32_bf16(b0_2, af0, acc[0][2], 0, 0, 0);
    acc[0][3] = __builtin_amdgcn_mfma_f32_16x16x32_bf16(b0_3, af0, acc[0][3], 0, 0, 0);
    acc[1][0] = __builtin_amdgcn_mfma_f32_16x16x32_bf16(b0_0, af1, acc[1][0], 0, 0, 0);
    acc[1][1] = __builtin_amdgcn_mfma_f32_16x16x32_bf16(b0_1, af1, acc[1][1], 0, 0, 0);
    acc[1][2] = __builtin_amdgcn_mfma_f32_16x16x32_bf16(b0_2, af1, acc[1][2], 0, 0, 0);
    acc[1][3] = __builtin_amdgcn_mfma_f32_16x16x32_bf16(b0_3, af1, acc[1][3], 0, 0, 0);
    b0_0 = b1_0; b0_1 = b1_1; b0_2 = b1_2; b0_3 = b1_3;
    b1_0 = b2_0; b1_1 = b2_1; b1_2 = b2_2; b1_3 = b2_3;
  }

  unsigned short* cT = lA;
  __syncthreads();
#pragma unroll
  for (int m = 0; m < 2; ++m) {
    const int rl = wr * 32 + m * 16 + r0;
#pragma unroll
    for (int n = 0; n < 4; ++n) {
      const int cl = wc * 64 + n * 16 + kq * 4;
      const f32x4 bv = *(const f32x4*)&bp[tileN + cl];
      float v0 = acc[m][n][0] + bv[0];
      float v1 = acc[m][n][1] + bv[1];
      float v2 = acc[m][n][2] + bv[2];
      float v3 = acc[m][n][3] + bv[3];
      if (act) {
        v0 = v0 > 0.f ? v0 : 128.f * v0;
        v1 = v1 > 0.f ? v1 : 128.f * v1;
        v2 = v2 > 0.f ? v2 : 128.f * v2;
        v3 = v3 > 0.f ? v3 : 128.f * v3;
      }
      uint2 pk;
      pk.x = (unsigned)f2b(v0) | ((unsigned)f2b(v1) << 16);
      pk.y = (unsigned)f2b(v2) | ((unsigned)f2b(v3) << 16);
      *(uint2*)&cT[rl * 132 + cl] = pk;
    }
  }
  __syncthreads();
#pragma unroll
  for (int it = 0; it < 4; ++it) {
    const int idx = it * 256 + tid;
    const int row = idx >> 4, ch = idx & 15;
    const uint4 val = *(const uint4*)&cT[row * 132 + ch * 8];
    *(uint4*)(Cp + (size_t)(tileM + row) * ldc + tileN + ch * 8) = val;
  }
}

// ---------------------------------------------------------------------------
// gemm64p v4 (unchanged from R22): persistent-A, XCD-type-partitioned,
// depth-4 B prefetch, LDS-only barriers.
// ---------------------------------------------------------------------------
__global__ __launch_bounds__(256) void gemm64p(
    const unsigned short* __restrict__ A, const unsigned short* __restrict__ Ab,
    const unsigned short* __restrict__ Wp, const unsigned short* __restrict__ Wpb,
    const float* __restrict__ bias, const float* __restrict__ biasb,
    unsigned short* __restrict__ C, unsigned short* __restrict__ Cb)
{
  const int K = 256, KT = 8;
  __shared__ __align__(16) unsigned short lA[64 * 256];
  __shared__ __align__(16) unsigned short cT[64 * 132];
  const int tid = threadIdx.x;
  const int lane = tid & 63;
  const int w = tid >> 6;
  const int wr = w >> 1, wc = w & 1;
  const int r0 = lane & 15, kq = lane >> 4;

  const int bx = (int)blockIdx.x;
  const int isopp = (bx & 4) >> 2;
  const int idxm = (bx >> 3) * 4 + (bx & 3);

  const unsigned short *Ap, *Wsel;
  const float* bp;
  unsigned short* Cp;
  if (!isopp) { Ap = A;  Wsel = Wp;  bp = bias;  Cp = C;  }
  else        { Ap = Ab; Wsel = Wpb; bp = biasb; Cp = Cb; }
  const int tileM = idxm * 64;

  for (int rd = 0; rd < KT; ++rd) {
    int idx = rd * 256 + tid;
    int row = idx >> 5;
    int g = idx & 31;
    load_lds16(Ap + (size_t)(tileM + row) * K + ((g ^ (row & 7)) << 3),
               (char*)lA + idx * 16);
  }

  const int rb0 = (wr * 32 + r0) * K;
  const int rb1 = (wr * 32 + 16 + r0) * K;
  const int rx = r0 & 7;

  __syncthreads();

  for (int nn = 0; nn < 12; ++nn) {
    const int cb = (int)blockIdx.y * 12 + nn;
    const int tileN = cb * 128;
    const int nblk0 = (tileN >> 4) + wc * 4;
    const unsigned short* wn0 = Wsel + ((size_t)(nblk0 + 0) * KT * 64 + lane) * 8;
    const unsigned short* wn1 = Wsel + ((size_t)(nblk0 + 1) * KT * 64 + lane) * 8;
    const unsigned short* wn2 = Wsel + ((size_t)(nblk0 + 2) * KT * 64 + lane) * 8;
    const unsigned short* wn3 = Wsel + ((size_t)(nblk0 + 3) * KT * 64 + lane) * 8;

    short8 bq[4][4];
#pragma unroll
    for (int sl = 0; sl < 4; ++sl) {
      const int o = sl * 512;
      bq[sl][0] = *(const short8*)(wn0 + o);
      bq[sl][1] = *(const short8*)(wn1 + o);
      bq[sl][2] = *(const short8*)(wn2 + o);
      bq[sl][3] = *(const short8*)(wn3 + o);
    }

    f32x4 acc[2][4];
#pragma unroll
    for (int m = 0; m < 2; ++m)
#pragma unroll
      for (int n = 0; n < 4; ++n)
        acc[m][n] = (f32x4){0.f, 0.f, 0.f, 0.f};

#pragma unroll
    for (int kt = 0; kt < KT; ++kt) {
      const int sl = kt & 3;
      short8 c0 = bq[sl][0], c1 = bq[sl][1], c2 = bq[sl][2], c3 = bq[sl][3];
      if (kt + 4 < KT) {
        const int o = (kt + 4) * 512;
        bq[sl][0] = *(const short8*)(wn0 + o);
        bq[sl][1] = *(const short8*)(wn1 + o);
        bq[sl][2] = *(const short8*)(wn2 + o);
        bq[sl][3] = *(const short8*)(wn3 + o);
      }
      const int p = (((kt << 2) + kq) ^ rx) * 8;
      short8 af0 = *(const short8*)&lA[rb0 + p];
      short8 af1 = *(const short8*)&lA[rb1 + p];
      acc[0][0] = __builtin_amdgcn_mfma_f32_16x16x32_bf16(c0, af0, acc[0][0], 0, 0, 0);
      acc[0][1] = __builtin_amdgcn_mfma_f32_16x16x32_bf16(c1, af0, acc[0][1], 0, 0, 0);
      acc[0][2] = __builtin_amdgcn_mfma_f32_16x16x32_bf16(c2, af0, acc[0][2], 0, 0, 0);
      acc[0][3] = __builtin_amdgcn_mfma_f32_16x16x32_bf16(c3, af0, acc[0][3], 0, 0, 0);
      acc[1][0] = __builtin_amdgcn_mfma_f32_16x16x32_bf16(c0, af1, acc[1][0], 0, 0, 0);
      acc[1][1] = __builtin_amdgcn_mfma_f32_16x16x32_bf16(c1, af1, acc[1][1], 0, 0, 0);
      acc[1][2] = __builtin_amdgcn_mfma_f32_16x16x32_bf16(c2, af1, acc[1][2], 0, 0, 0);
      acc[1][3] = __builtin_amdgcn_mfma_f32_16x16x32_bf16(c3, af1, acc[1][3], 0, 0, 0);
    }

    lds_barrier();
#pragma unroll
    for (int m = 0; m < 2; ++m) {
      const int rl = wr * 32 + m * 16 + r0;
#pragma unroll
      for (int n = 0; n < 4; ++n) {
        const int cl = wc * 64 + n * 16 + kq * 4;
        const f32x4 bv = *(const f32x4*)&bp[tileN + cl];
        uint2 pk;
        pk.x = (unsigned)f2b(acc[m][n][0] + bv[0]) |
               ((unsigned)f2b(acc[m][n][1] + bv[1]) << 16);
        pk.y = (unsigned)f2b(acc[m][n][2] + bv[2]) |
               ((unsigned)f2b(acc[m][n][3] + bv[3]) << 16);
        *(uint2*)&cT[rl * 132 + cl] = pk;
      }
    }
    lds_barrier();
    unsigned short* dstb = Cp + ((size_t)cb * NNODES + tileM) * 128;
#pragma unroll
    for (int it = 0; it < 4; ++it) {
      const int idx = it * 256 + tid;
      const uint4 val = *(const uint4*)&cT[(idx >> 4) * 132 + (idx & 15) * 8];
      *(uint4*)(dstb + (size_t)idx * 8) = val;
    }
  }
}

// ---------------------------------------------------------------------------
// GATv2 edge stage v11: group-per-(d,h), 16 lanes/group, CONFLICT-FREE lane
// mapping — lane owns channels {r*64 + lane16*4 .. +3}, so each LDS b64 read
// is 16 lanes x 8B contiguous (all 32 banks once per group). Sum over lanes
// is unchanged (channel assignment arbitrary before shfl reduce).
// ---------------------------------------------------------------------------
#define SX 260
__global__ __launch_bounds__(256) void gat_edge(
    const unsigned short* __restrict__ proj_my,
    const unsigned short* __restrict__ proj_op,
    const int* __restrict__ e_beats, const int* __restrict__ e_rl,
    const float* __restrict__ attL, const float* __restrict__ gbiasL,
    unsigned short* __restrict__ gat_op, unsigned short* __restrict__ gat_my)
{
  __shared__ __align__(16) unsigned short xl[48 * SX];
  __shared__ __align__(16) float attS[4 * SX];
  __shared__ __align__(16) float A2f[12 * 48];
  __shared__ int multI[144];
  __shared__ unsigned char srcG[12][12];
  __shared__ unsigned char multG[12][12];
  __shared__ int cntG[12];
  const int bid = blockIdx.x, tid = threadIdx.x;
  const int dir = bid >= NGR;
  const int g = dir ? bid - NGR : bid;
  const int base = g * 12;

  const unsigned short *Psrc, *Pdst;
  int pcol0;
  const int* edges;
  const float* att;
  const float* gbias;
  unsigned short* outp;
  if (!dir) {
    Psrc = proj_my; Pdst = proj_op; pcol0 = 0;
    edges = e_beats; att = attL; gbias = gbiasL; outp = gat_op;
  } else {
    Psrc = proj_op; Pdst = proj_my; pcol0 = 1024;
    edges = e_rl; att = attL + 1024; gbias = gbiasL + 256; outp = gat_my;
  }

  if (tid < 144) multI[tid] = 0;
  for (int i = tid; i < 576; i += 256) A2f[i] = 0.f;
  __syncthreads();
  if (tid < 72) {
    const int s = edges[g * 72 + tid] - base;
    const int d = edges[ETOT + g * 72 + tid] - base;
    atomicAdd(&multI[d * 12 + s], 1);
  }
  for (int i = tid; i < 1024; i += 256)
    attS[(i >> 8) * SX + (i & 255)] = att[i];
  for (int i = tid; i < 3072; i += 256) {
    int s = i >> 8, c4 = (i & 255) * 4;
    int h = c4 >> 8, cc = c4 & 255;
    *(ushort4*)&xl[(h * 12 + s) * SX + cc] =
        *(const ushort4*)pnode(Psrc, pcol0 + c4, base + s);
  }
  __syncthreads();

  if (tid < 12) {
    int n = 0;
    for (int s = 0; s < 12; ++s) {
      const int m = multI[tid * 12 + s];
      if (m > 0) { srcG[tid][n] = (unsigned char)s; multG[tid][n] = (unsigned char)m; ++n; }
    }
    cntG[tid] = n;
  }
  __syncthreads();

  for (int r3 = 0; r3 < 3; ++r3) {
    const int slot = r3 * 256 + tid;
    const int g16 = slot >> 4, lane16 = slot & 15;
    const int d = g16 >> 2, h = g16 & 3;
    const int cnt = cntG[d];
    // channel chunks: chunk r covers channels r*64 + lane16*4 .. +3
    const int c0ch = lane16 * 4;
    const ushort4 xr0 = *(const ushort4*)pnode(Pdst, pcol0 + h * 256 +   0 + c0ch, base + d);
    const ushort4 xr1 = *(const ushort4*)pnode(Pdst, pcol0 + h * 256 +  64 + c0ch, base + d);
    const ushort4 xr2 = *(const ushort4*)pnode(Pdst, pcol0 + h * 256 + 128 + c0ch, base + d);
    const ushort4 xr3 = *(const ushort4*)pnode(Pdst, pcol0 + h * 256 + 192 + c0ch, base + d);
    const float* pa = &attS[h * SX + c0ch];
    const f32x4 at0 = *(const f32x4*)(pa);
    const f32x4 at1 = *(const f32x4*)(pa + 64);
    const f32x4 at2 = *(const f32x4*)(pa + 128);
    const f32x4 at3 = *(const f32x4*)(pa + 192);

    float myalpha = -1e30f;
    for (int j = 0; j < cnt; ++j) {
      const int s = srcG[d][j];
      const unsigned short* pl = &xl[(h * 12 + s) * SX + c0ch];
      float p = 0.f;
      {
        ushort4 a4 = *(const ushort4*)(pl);
        float v0 = b2f(a4.x) + b2f(xr0.x); v0 = fmaxf(v0, 0.2f * v0);
        float v1 = b2f(a4.y) + b2f(xr0.y); v1 = fmaxf(v1, 0.2f * v1);
        float v2 = b2f(a4.z) + b2f(xr0.z); v2 = fmaxf(v2, 0.2f * v2);
        float v3 = b2f(a4.w) + b2f(xr0.w); v3 = fmaxf(v3, 0.2f * v3);
        p = fmaf(v0, at0[0], p); p = fmaf(v1, at0[1], p);
        p = fmaf(v2, at0[2], p); p = fmaf(v3, at0[3], p);
      }
      {
        ushort4 a4 = *(const ushort4*)(pl + 64);
        float v0 = b2f(a4.x) + b2f(xr1.x); v0 = fmaxf(v0, 0.2f * v0);
        float v1 = b2f(a4.y) + b2f(xr1.y); v1 = fmaxf(v1, 0.2f * v1);
        float v2 = b2f(a4.z) + b2f(xr1.z); v2 = fmaxf(v2, 0.2f * v2);
        float v3 = b2f(a4.w) + b2f(xr1.w); v3 = fmaxf(v3, 0.2f * v3);
        p = fmaf(v0, at1[0], p); p = fmaf(v1, at1[1], p);
        p = fmaf(v2, at1[2], p); p = fmaf(v3, at1[3], p);
      }
      {
        ushort4 a4 = *(const ushort4*)(pl + 128);
        float v0 = b2f(a4.x) + b2f(xr2.x); v0 = fmaxf(v0, 0.2f * v0);
        float v1 = b2f(a4.y) + b2f(xr2.y); v1 = fmaxf(v1, 0.2f * v1);
        float v2 = b2f(a4.z) + b2f(xr2.z); v2 = fmaxf(v2, 0.2f * v2);
        float v3 = b2f(a4.w) + b2f(xr2.w); v3 = fmaxf(v3, 0.2f * v3);
        p = fmaf(v0, at2[0], p); p = fmaf(v1, at2[1], p);
        p = fmaf(v2, at2[2], p); p = fmaf(v3, at2[3], p);
      }
      {
        ushort4 a4 = *(const ushort4*)(pl + 192);
        float v0 = b2f(a4.x) + b2f(xr3.x); v0 = fmaxf(v0, 0.2f * v0);
        float v1 = b2f(a4.y) + b2f(xr3.y); v1 = fmaxf(v1, 0.2f * v1);
        float v2 = b2f(a4.z) + b2f(xr3.z); v2 = fmaxf(v2, 0.2f * v2);
        float v3 = b2f(a4.w) + b2f(xr3.w); v3 = fmaxf(v3, 0.2f * v3);
        p = fmaf(v0, at3[0], p); p = fmaf(v1, at3[1], p);
        p = fmaf(v2, at3[2], p); p = fmaf(v3, at3[3], p);
      }
#pragma unroll
      for (int off = 1; off < 16; off <<= 1) p += __shfl_xor(p, off, 64);
      if (j == lane16) myalpha = p * LOG2E;
    }
    float m = myalpha;
#pragma unroll
    for (int off = 1; off < 16; off <<= 1) m = fmaxf(m, __shfl_xor(m, off, 64));
    const float wv = __builtin_amdgcn_exp2f(myalpha - m);
    const float mw = (lane16 < cnt) ? (float)multG[d][lane16] * wv : 0.f;
    float den = mw;
#pragma unroll
    for (int off = 1; off < 16; off <<= 1) den += __shfl_xor(den, off, 64);
    const float inv = 0.25f * __builtin_amdgcn_rcpf(den + 1e-16f);
    if (lane16 < cnt) A2f[d * 48 + h * 12 + srcG[d][lane16]] = mw * inv;
  }
  __syncthreads();

  {
    const int c = tid;
    float xlv[48];
#pragma unroll
    for (int j = 0; j < 48; ++j) xlv[j] = b2f(xl[j * SX + c]);
    const float gb = gbias[c];
#pragma unroll
    for (int d = 0; d < 12; ++d) {
      const f32x4* arow = (const f32x4*)&A2f[d * 48];
      float s = 0.f;
#pragma unroll
      for (int jj = 0; jj < 12; ++jj) {
        f32x4 a4 = arow[jj];
        s = fmaf(a4.x, xlv[jj * 4 + 0], s);
        s = fmaf(a4.y, xlv[jj * 4 + 1], s);
        s = fmaf(a4.z, xlv[jj * 4 + 2], s);
        s = fmaf(a4.w, xlv[jj * 4 + 3], s);
      }
      outp[(size_t)(base + d) * 256 + c] = f2b(s + gb);
    }
  }
}

// ---------------------------------------------------------------------------
// cg_fused v2 (unchanged): dedup'd CGConv combine + node MFMA.
// ---------------------------------------------------------------------------
__global__ __launch_bounds__(256) void cg_fused(
    const unsigned short* __restrict__ proj_my,
    const unsigned short* __restrict__ proj_op,
    unsigned short* __restrict__ Hmy, unsigned short* __restrict__ Hopp,
    const unsigned short* __restrict__ gat_my, const unsigned short* __restrict__ gat_op,
    const int* __restrict__ e_loses, const int* __restrict__ e_rb,
    const unsigned short* __restrict__ node_wtL, const float* __restrict__ node_bL)
{
  __shared__ __align__(8) unsigned short df[3072], dsb[3072];
  __shared__ __align__(8) unsigned short sfb[3072], ssb[3072];
  __shared__ __align__(16) unsigned short At[16 * 264];
  __shared__ int multI[144];
  __shared__ unsigned char srcG[12][12];
  __shared__ unsigned char multG[12][12];
  __shared__ int cntG[12];
  const int bid = blockIdx.x, tid = threadIdx.x;
  const int dir = bid >= NGR;
  const int g = dir ? bid - NGR : bid;
  const int base = g * 12;

  const unsigned short *Pd, *Ps, *gatp;
  unsigned short *Hout;
  int fcol, scol;
  const int* edges;
  if (!dir) {
    Pd = proj_op; Ps = proj_my; fcol = 2048; scol = 2304;
    Hout = Hopp; gatp = gat_op; edges = e_loses;
  } else {
    Pd = proj_my; Ps = proj_op; fcol = 2560; scol = 2816;
    Hout = Hmy; gatp = gat_my; edges = e_rb;
  }

  if (tid < 144) multI[tid] = 0;
  __syncthreads();
  if (tid < 72) {
    const int s = edges[g * 72 + tid] - base;
    const int d = edges[ETOT + g * 72 + tid] - base;
    atomicAdd(&multI[d * 12 + s], 1);
  }
  for (int i = tid; i < 768; i += 256) {
    int s = i >> 6, c4 = (i & 63) * 4;
    const int node = base + s;
    *(ushort4*)&df[s * 256 + c4]  = *(const ushort4*)pnode(Pd, fcol + c4, node);
    *(ushort4*)&dsb[s * 256 + c4] = *(const ushort4*)pnode(Pd, scol + c4, node);
    *(ushort4*)&sfb[s * 256 + c4] = *(const ushort4*)pnode(Ps, fcol + c4, node);
    *(ushort4*)&ssb[s * 256 + c4] = *(const ushort4*)pnode(Ps, scol + c4, node);
  }
  const int c = tid;
  float hv[12], gv[12];
#pragma unroll
  for (int d = 0; d < 12; ++d) {
    const size_t o = (size_t)(base + d) * 256 + c;
    hv[d] = b2f(Hout[o]);
    gv[d] = b2f(gatp[o]);
  }
  __syncthreads();
  if (tid < 12) {
    int n = 0;
    for (int s = 0; s < 12; ++s) {
      const int m = multI[tid * 12 + s];
      if (m > 0) { srcG[tid][n] = (unsigned char)s; multG[tid][n] = (unsigned char)m; ++n; }
    }
    cntG[tid] = n;
  }
  __syncthreads();
  for (int d = 0; d < 12; ++d) {
    const float fd = b2f(df[d * 256 + c]);
    const float sd = b2f(dsb[d * 256 + c]);
    const int n = cntG[d];
    float acc = 0.f;
    for (int j = 0; j < n; ++j) {
      const int s = srcG[d][j];
      const float mlt = (float)multG[d][j];
      const float zf = fd + b2f(sfb[s * 256 + c]);
      const float zs = sd + b2f(ssb[s * 256 + c]);
      const float gate = __builtin_amdgcn_rcpf(1.f + __builtin_amdgcn_exp2f(-LOG2E * zf));
      const float e2 = __builtin_amdgcn_exp2f(-LOG2E * fabsf(zs));
      const float sp = fmaxf(zs, 0.f) + LN2 * __builtin_amdgcn_logf(1.f + e2);
      acc = fmaf(mlt * gate, sp, acc);
    }
    At[d * 264 + c] = f2b(hv[d] + gv[d] + acc);
  }
  __syncthreads();
  {
    const int w = tid >> 6, lane = tid & 63;
    const int r0 = lane & 15, kq = lane >> 4;
#pragma unroll
    for (int n = 0; n < 4; ++n) {
      const unsigned short* wb = node_wtL + ((size_t)(w * 4 + n) * 8) * 512 + lane * 8;
      f32x4 a = (f32x4){0.f, 0.f, 0.f, 0.f};
#pragma unroll
      for (int kt = 0; kt < 8; ++kt) {
        short8 wf = *(const short8*)(wb + kt * 512);
        short8 af = *(const short8*)&At[r0 * 264 + kt * 32 + kq * 8];
        a = __builtin_amdgcn_mfma_f32_16x16x32_bf16(wf, af, a, 0, 0, 0);
      }
      if (r0 < 12) {
        const int col0 = w * 64 + n * 16 + kq * 4;
        const f32x4 bv = *(const f32x4*)&node_bL[col0];
        uint2 pk;
        pk.x = (unsigned)f2b(a[0] + bv[0]) | ((unsigned)f2b(a[1] + bv[1]) << 16);
        pk.y = (unsigned)f2b(a[2] + bv[2]) | ((unsigned)f2b(a[3] + bv[3]) << 16);
        *(uint2*)(Hout + (size_t)(base + r0) * 256 + col0) = pk;
      }
    }
  }
}

// ---------------------------------------------------------------------------
// logits: one wave per node, dot(f[128], W2) + b2
// ---------------------------------------------------------------------------
__global__ __launch_bounds__(256) void logits_kernel(
    const unsigned short* __restrict__ f, const float* __restrict__ W2,
    const float* __restrict__ b2, float* __restrict__ out)
{
  const int node = blockIdx.x * 4 + (threadIdx.x >> 6);
  const int lane = threadIdx.x & 63;
  const size_t o = (size_t)node * 128 + lane * 2;
  float s = b2f(f[o]) * W2[lane * 2] + b2f(f[o + 1]) * W2[lane * 2 + 1];
  for (int d = 32; d > 0; d >>= 1) s += __shfl_down(s, d, 64);
  if (lane == 0) out[node] = s + b2[0];
}

// ---------------------------------------------------------------------------
extern "C" void kernel_launch(void* const* d_in, const int* in_sizes, int n_in,
                              void* d_out, int out_size, void* d_ws, size_t ws_size,
                              hipStream_t stream) {
  const float* x_my    = (const float*)d_in[0];
  const float* x_opp   = (const float*)d_in[1];
  const int*   e_beats = (const int*)d_in[2];
  const int*   e_loses = (const int*)d_in[3];
  const int*   e_rb    = (const int*)d_in[4];
  const int*   e_rl    = (const int*)d_in[5];
  const float* enc_W   = (const float*)d_in[7];
  const float* enc_b   = (const float*)d_in[8];
  const float* gat_Wl  = (const float*)d_in[9];
  const float* gat_bl  = (const float*)d_in[10];
  const float* gat_Wr  = (const float*)d_in[11];
  const float* gat_br  = (const float*)d_in[12];
  const float* gat_att = (const float*)d_in[13];
  const float* gat_bsp = (const float*)d_in[14];
  const float* cg_Wf   = (const float*)d_in[15];
  const float* cg_bf   = (const float*)d_in[16];
  const float* cg_Ws   = (const float*)d_in[17];
  const float* cg_bs   = (const float*)d_in[18];
  const float* node_W  = (const float*)d_in[19];
  const float* node_b  = (const float*)d_in[20];
  const float* fin_W1  = (const float*)d_in[21];
  const float* fin_b1  = (const float*)d_in[22];
  const float* fin_W2  = (const float*)d_in[23];
  const float* fin_b2  = (const float*)d_in[24];

  char* wsp = (char*)d_ws;
  size_t off = 0;
  auto alloc = [&](size_t b) { char* p = wsp + off; off += (b + 255) & ~(size_t)255; return p; };
  unsigned short* wt_my   = (unsigned short*)alloc((size_t)2359296 * 2);
  unsigned short* wt_opp  = (unsigned short*)alloc((size_t)2359296 * 2);
  unsigned short* node_wt = (unsigned short*)alloc((size_t)196608 * 2);
  unsigned short* enc_wt  = (unsigned short*)alloc((size_t)8192 * 2);
  unsigned short* fin_w1t = (unsigned short*)alloc((size_t)32768 * 2);
  float*          bias_my = (float*)alloc((size_t)9216 * 4);
  float*          bias_op = (float*)alloc((size_t)9216 * 4);
  unsigned short* xb      = (unsigned short*)alloc((size_t)786432 * 2);
  unsigned short* Hb      = (unsigned short*)alloc((size_t)2 * NNODES * 256 * 2);
  unsigned short* proj_my = (unsigned short*)alloc((size_t)NNODES * 3072 * 2);
  unsigned short* proj_op = (unsigned short*)alloc((size_t)NNODES * 3072 * 2);
  unsigned short* gat_my  = (unsigned short*)alloc((size_t)NNODES * 256 * 2);
  unsigned short* gat_op  = (unsigned short*)alloc((size_t)NNODES * 256 * 2);
  unsigned short* fbuf    = (unsigned short*)alloc((size_t)NNODES * 128 * 2);

  const int PACK_TOTAL = 2 * 2359296 + 196608 + 8192 + 32768 + 2 * 9216 + 2 * 393216;
  pack_kernel<<<(PACK_TOTAL + 255) / 256, 256, 0, stream>>>(
      gat_Wl, gat_Wr, cg_Wf, cg_Ws, node_W, enc_W, fin_W1,
      gat_bl, gat_br, cg_bf, cg_bs, x_my, x_opp,
      wt_my, wt_opp, node_wt, enc_wt, fin_w1t, bias_my, bias_op, xb);

  unsigned short* Hmy  = Hb;
  unsigned short* Hopp = Hb + (size_t)NNODES * 256;

  // encoder: h = x @ enc_W + enc_b  (M = 24576, N = 256, K = 32)
  gemm64<<<dim3(384, 2), 256, 0, stream>>>(
      xb, xb, 32, enc_wt, enc_wt, enc_b, enc_b, Hb, Hb, 256, 32, 0, 384);

  for (int l = 0; l < 3; ++l) {
    gemm64p<<<dim3(384, 2), 256, 0, stream>>>(
        Hmy, Hopp,
        wt_my + (size_t)l * 786432, wt_opp + (size_t)l * 786432,
        bias_my + l * 3072, bias_op + l * 3072,
        proj_my, proj_op);
    gat_edge<<<2 * NGR, 256, 0, stream>>>(
        proj_my, proj_op, e_beats, e_rl,
        gat_att + l * 2048, gat_bsp + l * 512, gat_op, gat_my);
    cg_fused<<<2 * NGR, 256, 0, stream>>>(
        proj_my, proj_op, Hmy, Hopp, gat_my, gat_op,
        e_loses, e_rb,
        node_wt + (size_t)l * 65536, node_b + l * 256);
  }

  gemm64<<<dim3(192, 1), 256, 0, stream>>>(
      Hmy, Hmy, 256, fin_w1t, fin_w1t, fin_b1, fin_b1, fbuf, fbuf, 128, 256, 1, 192);
  logits_kernel<<<NNODES / 4, 256, 0, stream>>>(fbuf, fin_W2, fin_b2, (float*)d_out);
}